// Round 4
// baseline (15455.638 us; speedup 1.0000x reference)
//
#include <hip/hip_runtime.h>
#include <hip/hip_bf16.h>

// IN=128, H=512, N=2048, W=64, OUT=128, R=4, T=128, B=64
// gate K=896 (x 0:128 | read_vec 128:384 | h 384:896), gate rows 2048
// Wkb rows: 0..127 = Wout, 128..447 = Wkey (read keys 128..383, write key 384..447)
#define EPSF 1e-8f

typedef __attribute__((ext_vector_type(8))) __bf16 bf8;
typedef __attribute__((ext_vector_type(4))) float f4;

__device__ __forceinline__ short f2bf(float f) {
  union { __hip_bfloat16 b; short s; } u;
  u.b = __float2bfloat16(f);
  return u.s;
}
__device__ __forceinline__ float sigf(float x) { return 1.f / (1.f + __expf(-x)); }
__device__ __forceinline__ float red16(float v) {
  v += __shfl_xor(v, 1); v += __shfl_xor(v, 2);
  v += __shfl_xor(v, 4); v += __shfl_xor(v, 8);
  return v;
}

// Grid barrier round k=1,2,...: single monotonic arrival counter bar[0];
// releaser (256th arriver of round k) stores k to 8 flag lines bar[16+g*16].
// Pollers use relaxed atomic RMW (coherence-point read, no per-poll cache inv).
__device__ __forceinline__ void gsync(unsigned* bar, unsigned k) {
  __syncthreads();
  if (threadIdx.x == 0) {
    __threadfence();
    unsigned old = __hip_atomic_fetch_add(&bar[0], 1u, __ATOMIC_RELAXED,
                                          __HIP_MEMORY_SCOPE_AGENT);
    if (old == k * 256u - 1u) {
      for (int j = 0; j < 8; ++j)
        __hip_atomic_store(&bar[16 + j * 16], k, __ATOMIC_RELAXED,
                           __HIP_MEMORY_SCOPE_AGENT);
    }
    const unsigned g = blockIdx.x >> 5;
    while (__hip_atomic_fetch_add(&bar[16 + g * 16], 0u, __ATOMIC_RELAXED,
                                  __HIP_MEMORY_SCOPE_AGENT) < k)
      __builtin_amdgcn_s_sleep(2);
    __threadfence();
  }
  __syncthreads();
}

__global__ __launch_bounds__(512) void mann_mega(
    const float* __restrict__ x_seq, const float* __restrict__ Wih,
    const float* __restrict__ Whh, const float* __restrict__ bih,
    const float* __restrict__ bhh, const float* __restrict__ Wout,
    const float* __restrict__ boutp, const float* __restrict__ Wkey,
    const float* __restrict__ bkeyp, const float* __restrict__ alphap,
    const float* __restrict__ gammap, float* __restrict__ out, char* ws) {
  float* M = (float*)(ws);                     // 33554432
  float* rwb0 = (float*)(ws + 33554432);       // 2097152  exps [b][n][r] f4
  float* rwb1 = (float*)(ws + 35651584);       // 2097152
  float* usage = (float*)(ws + 37748736);      // 524288
  float* cst = (float*)(ws + 38273024);        // 131072
  short* hb0 = (short*)(ws + 38404096);        // 65536
  short* hb1 = (short*)(ws + 38469632);        // 65536
  float* rvp = (float*)(ws + 38535168);        // 262144 rv partials [b][ch][256]
  float* dp = (float*)(ws + 38797312);         // 4096   denom partials [b][r][ch]
  float* sd0 = (float*)(ws + 38801408);        // 1024   denoms [b][r]
  float* sd1 = (float*)(ws + 38802432);        // 1024
  int* lu = (int*)(ws + 38803456);             // 256
  unsigned* bar = (unsigned*)(ws + 38803712);  // 1024 (host memset 0)
  short* Wc = (short*)(ws + 38804736);         // 3670016
  short* Wkb = (short*)(ws + 42474752);        // 458752 -> end 42933504

  __shared__ union {
    struct { short Xs[64 * 904]; } g;          // P1 gates: full-K X panel
    struct { float sv[512]; int si[512]; } m;  // P1 usage argmin
    struct { short hs[512]; float kbuf[256]; float wkbuf[64];
             float rvacc[256]; float wsum[32]; } a;  // PA
  } sm;
  __shared__ float gbuf[64 * 33];
  __shared__ float denl[256];

  const int tid = threadIdx.x;
  const int lane = tid & 63;
  const int wv = tid >> 6;
  const int s = lane & 15;
  const int q = lane >> 4;
  unsigned rnd = 0;

  // ---------------- prologue ----------------
  {
    const unsigned gid = blockIdx.x * 512 + tid;
    const unsigned gs = 256 * 512;
    for (unsigned i = gid; i < 2048u * 896u; i += gs) {
      unsigned row = i / 896u, k = i - row * 896u;
      float v = (k < 384u) ? Wih[row * 384u + k] : Whh[row * 512u + (k - 384u)];
      Wc[i] = f2bf(v);
    }
    for (unsigned i = gid; i < 448u * 512u; i += gs) {
      unsigned row = i >> 9, k = i & 511u;
      float v = (row < 128u) ? Wout[row * 512u + k] : Wkey[(row - 128u) * 512u + k];
      Wkb[i] = f2bf(v);
    }
    for (unsigned i = gid; i < 8388608u; i += gs) M[i] = 1e-6f;
    for (unsigned i = gid; i < 524288u; i += gs) rwb1[i] = 0.f;  // exp_{-1}=0
    for (unsigned i = gid; i < 131072u; i += gs) usage[i] = 0.f;
    if (gid < 32768u) { cst[gid] = 0.f; hb1[gid] = 0; }
    for (unsigned i = gid; i < 65536u; i += gs) rvp[i] = 0.f;
    if (gid < 1024u) dp[gid] = 0.25f;  // denom_{-1}=1 -> rv_{-1}=0
    if (gid < 256u) sd1[gid] = 1.f;    // denom_{-1}=1
    if (gid < 64u) lu[gid] = 0;        // argmin(usage_{-1}=0) = 0
  }
  gsync(bar, ++rnd);

  for (int t = 0; t < 128; ++t) {
    const int p = t & 1;
    short* hN = p ? hb1 : hb0;
    const short* hP = p ? hb0 : hb1;
    float* rwCur = p ? rwb1 : rwb0;       // exps of step t (written in PA)
    const float* rwM1 = p ? rwb0 : rwb1;  // exps of step t-1
    const float* rwM2 = rwCur;            // exps of step t-2 (stale content)
    float* sdM1w = p ? sd0 : sd1;         // denoms of step t-1 (stored this P1)
    const float* sdM1 = sdM1w;
    const float* sdM2 = p ? sd1 : sd0;    // denoms of step t-2

    // ========== P1 phase ==========
    if (blockIdx.x < 64) {
      const int j0 = blockIdx.x * 8;
      if (tid < 256) {
        float d = dp[tid * 4 + 0] + dp[tid * 4 + 1] + dp[tid * 4 + 2] + dp[tid * 4 + 3];
        denl[tid] = 1.f / d;  // inv denom_{t-1}[b*4+r]
      }
      __syncthreads();
      // stage full X panel [64 x 896] bf16, padded stride 904
      for (int it = 0; it < 28; ++it) {
        int i4 = it * 512 + tid;  // short4 index, 0..14335
        int e = i4 * 4;
        int row = e / 896, k = e - row * 896;
        short4 o;
        if (k < 128) {
          float4 v = *(const float4*)&x_seq[((size_t)t * 64 + row) * 128 + k];
          o.x = f2bf(v.x); o.y = f2bf(v.y); o.z = f2bf(v.z); o.w = f2bf(v.w);
        } else if (k < 384) {
          int col = k - 128;
          float iv = denl[row * 4 + (col >> 6)];
          float a0 = 0, a1 = 0, a2 = 0, a3 = 0;
#pragma unroll
          for (int cc = 0; cc < 4; ++cc) {
            float4 v = *(const float4*)&rvp[(row * 4 + cc) * 256 + col];
            a0 += v.x; a1 += v.y; a2 += v.z; a3 += v.w;
          }
          o.x = f2bf(a0 * iv); o.y = f2bf(a1 * iv);
          o.z = f2bf(a2 * iv); o.w = f2bf(a3 * iv);
        } else {
          o = *(const short4*)&hP[row * 512 + (k - 384)];
        }
        *(short4*)&sm.g.Xs[row * 904 + k] = o;
      }
      __syncthreads();
      // MFMA: 8 waves = 4 m-slices x 2 n-halves; B-operand direct from L2
      {
        const int msl = wv >> 1, nh = wv & 1;
        const int rr = nh * 16 + s;
        const int gg = rr >> 3, jj = rr & 7;
        const size_t wrow = (size_t)(gg * 512 + j0 + jj) * 896;
        f4 acc = {0.f, 0.f, 0.f, 0.f};
#pragma unroll
        for (int kk = 0; kk < 28; ++kk) {
          bf8 a = *(const bf8*)&sm.g.Xs[(msl * 16 + s) * 904 + kk * 32 + q * 8];
          bf8 b = *(const bf8*)&Wc[wrow + kk * 32 + q * 8];
          acc = __builtin_amdgcn_mfma_f32_16x16x32_bf16(a, b, acc, 0, 0, 0);
        }
#pragma unroll
        for (int reg = 0; reg < 4; ++reg) {
          int bat = msl * 16 + q * 4 + reg;
          gbuf[bat * 33 + rr] = acc[reg];
        }
      }
      __syncthreads();
      {
        int b = tid & 63, jj = tid >> 6, j = j0 + jj;
        float gi = gbuf[b * 33 + jj] + bih[j] + bhh[j];
        float gf = gbuf[b * 33 + 8 + jj] + bih[512 + j] + bhh[512 + j];
        float gg2 = gbuf[b * 33 + 16 + jj] + bih[1024 + j] + bhh[1024 + j];
        float go = gbuf[b * 33 + 24 + jj] + bih[1536 + j] + bhh[1536 + j];
        float co = cst[b * 512 + j];
        float cn = sigf(gf) * co + sigf(gi) * tanhf(gg2);
        float hn = sigf(go) * tanhf(cn);
        cst[b * 512 + j] = cn;
        hN[b * 512 + j] = f2bf(hn);
      }
    } else if (blockIdx.x < 128 && t > 0) {
      // finalize step t-1: denoms -> sd, usage update, argmin -> lu_t
      const int b = blockIdx.x - 64;
      float idenC[4], idenO[4];
#pragma unroll
      for (int r = 0; r < 4; ++r) {
        float d = dp[(b * 4 + r) * 4 + 0] + dp[(b * 4 + r) * 4 + 1] +
                  dp[(b * 4 + r) * 4 + 2] + dp[(b * 4 + r) * 4 + 3];
        idenC[r] = 1.f / d;
        if (tid == 0) sdM1w[b * 4 + r] = d;
        idenO[r] = 1.f / sdM2[b * 4 + r];
      }
      const float sa = sigf(alphap[0]);
      const float ga = gammap[0];
      const int luB = lu[b];
      float vm = INFINITY;
      int im = 0x7fffffff;
      for (int i = 0; i < 4; ++i) {
        int n = i * 512 + tid;
        float4 eC = *(const float4*)&rwM1[((size_t)b * 2048 + n) * 4];
        float4 eO = *(const float4*)&rwM2[((size_t)b * 2048 + n) * 4];
        float wps = eO.x * idenO[0] + eO.y * idenO[1] + eO.z * idenO[2] + eO.w * idenO[3];
        float ww = sa * wps + (1.f - sa) * ((n == luB) ? 1.f : 0.f);
        float sn = eC.x * idenC[0] + eC.y * idenC[1] + eC.z * idenC[2] + eC.w * idenC[3];
        float u = ga * usage[b * 2048 + n] + sn + ww;
        usage[b * 2048 + n] = u;
        if (u < vm) { vm = u; im = n; }
      }
      sm.m.sv[tid] = vm; sm.m.si[tid] = im;
      __syncthreads();
      for (int off = 256; off > 0; off >>= 1) {
        if (tid < off) {
          float v2 = sm.m.sv[tid + off]; int j2 = sm.m.si[tid + off];
          if (v2 < sm.m.sv[tid] || (v2 == sm.m.sv[tid] && j2 < sm.m.si[tid])) {
            sm.m.sv[tid] = v2; sm.m.si[tid] = j2;
          }
        }
        __syncthreads();
      }
      if (tid == 0) lu[b] = sm.m.si[0];
    }
    gsync(bar, ++rnd);

    // ========== PA phase: keys/out + single fused M-pass ==========
    {
      const int b = blockIdx.x >> 2, ch = blockIdx.x & 3;
      if (tid < 128) *(short4*)&sm.a.hs[tid * 4] = *(const short4*)&hN[b * 512 + tid * 4];
      if (tid < 256) sm.a.rvacc[tid] = 0.f;
      __syncthreads();
      // keys (redundant per block) + out slice: 352 rows = 11 passes x 32
      for (int pp = 0; pp < 11; ++pp) {
        int idx = pp * 32 + wv * 4 + q;
        int wr; float bias;
        if (idx < 320) { wr = 128 + idx; bias = bkeyp[idx]; }
        else { wr = ch * 32 + (idx - 320); bias = boutp[wr]; }
        float acc = 0.f;
#pragma unroll
        for (int i = 0; i < 4; ++i) {
          bf8 w8 = *(const bf8*)&Wkb[(size_t)wr * 512 + i * 128 + s * 8];
          bf8 h8 = *(const bf8*)&sm.a.hs[i * 128 + s * 8];
#pragma unroll
          for (int j = 0; j < 8; ++j) acc += (float)w8[j] * (float)h8[j];
        }
        acc = red16(acc) + bias;
        if (s == 0) {
          if (idx < 256) sm.a.kbuf[idx] = acc;
          else if (idx < 320) sm.a.wkbuf[idx - 256] = acc;
          else out[((size_t)t * 64 + b) * 128 + wr] = acc;
        }
      }
      __syncthreads();
      float4 kn[4];
#pragma unroll
      for (int r = 0; r < 4; ++r) {
        float4 k4 = *(float4*)&sm.a.kbuf[r * 64 + s * 4];
        float ss = k4.x * k4.x + k4.y * k4.y + k4.z * k4.z + k4.w * k4.w;
        ss = red16(ss);
        float iv = 1.f / (sqrtf(ss) + EPSF);
        kn[r].x = k4.x * iv; kn[r].y = k4.y * iv;
        kn[r].z = k4.z * iv; kn[r].w = k4.w * iv;
      }
      const float4 wk = *(float4*)&sm.a.wkbuf[s * 4];
      float ipd[4];
#pragma unroll
      for (int r = 0; r < 4; ++r) ipd[r] = 1.f / sdM1[b * 4 + r];
      const float sa = sigf(alphap[0]);
      const int luB = lu[b];
      float4* M4 = (float4*)M;
      float4 rv0 = {0,0,0,0}, rv1 = {0,0,0,0}, rv2 = {0,0,0,0}, rv3 = {0,0,0,0};
      float es0 = 0.f, es1 = 0.f, es2 = 0.f, es3 = 0.f;
      for (int i = 0; i < 16; ++i) {
        const int n = ch * 512 + wv * 64 + i * 4 + q;
        const size_t mi = ((size_t)b * 2048 + n) * 16 + s;
        float4 m4 = M4[mi];
        float4 ep = *(const float4*)&rwM1[((size_t)b * 2048 + n) * 4];
        float ssm = m4.x * m4.x + m4.y * m4.y + m4.z * m4.z + m4.w * m4.w;
        float d0 = m4.x * kn[0].x + m4.y * kn[0].y + m4.z * kn[0].z + m4.w * kn[0].w;
        float d1 = m4.x * kn[1].x + m4.y * kn[1].y + m4.z * kn[1].z + m4.w * kn[1].w;
        float d2 = m4.x * kn[2].x + m4.y * kn[2].y + m4.z * kn[2].z + m4.w * kn[2].w;
        float d3 = m4.x * kn[3].x + m4.y * kn[3].y + m4.z * kn[3].z + m4.w * kn[3].w;
        ssm = red16(ssm);
        d0 = red16(d0); d1 = red16(d1); d2 = red16(d2); d3 = red16(d3);
        float iv = 1.f / (sqrtf(ssm) + EPSF);
        float e0 = __expf(d0 * iv), e1 = __expf(d1 * iv);
        float e2 = __expf(d2 * iv), e3 = __expf(d3 * iv);
        rv0.x += e0 * m4.x; rv0.y += e0 * m4.y; rv0.z += e0 * m4.z; rv0.w += e0 * m4.w;
        rv1.x += e1 * m4.x; rv1.y += e1 * m4.y; rv1.z += e1 * m4.z; rv1.w += e1 * m4.w;
        rv2.x += e2 * m4.x; rv2.y += e2 * m4.y; rv2.z += e2 * m4.z; rv2.w += e2 * m4.w;
        rv3.x += e3 * m4.x; rv3.y += e3 * m4.y; rv3.z += e3 * m4.z; rv3.w += e3 * m4.w;
        if (s == 0) {
          float4 ev; ev.x = e0; ev.y = e1; ev.z = e2; ev.w = e3;
          *(float4*)&rwCur[((size_t)b * 2048 + n) * 4] = ev;
          es0 += e0; es1 += e1; es2 += e2; es3 += e3;
        }
        float wps = ep.x * ipd[0] + ep.y * ipd[1] + ep.z * ipd[2] + ep.w * ipd[3];
        float onehot = (n == luB) ? 1.f : 0.f;
        float ww = sa * wps + (1.f - sa) * onehot;
        float keep = 1.f - onehot;
        float4 mn;
        mn.x = m4.x * keep + ww * wk.x;
        mn.y = m4.y * keep + ww * wk.y;
        mn.z = m4.z * keep + ww * wk.z;
        mn.w = m4.w * keep + ww * wk.w;
        M4[mi] = mn;
      }
      es0 += __shfl_xor(es0, 16); es0 += __shfl_xor(es0, 32);
      es1 += __shfl_xor(es1, 16); es1 += __shfl_xor(es1, 32);
      es2 += __shfl_xor(es2, 16); es2 += __shfl_xor(es2, 32);
      es3 += __shfl_xor(es3, 16); es3 += __shfl_xor(es3, 32);
      if (lane == 0) {
        sm.a.wsum[wv * 4 + 0] = es0; sm.a.wsum[wv * 4 + 1] = es1;
        sm.a.wsum[wv * 4 + 2] = es2; sm.a.wsum[wv * 4 + 3] = es3;
      }
#define REDQ(v) { v += __shfl_xor(v, 16); v += __shfl_xor(v, 32); }
      REDQ(rv0.x) REDQ(rv0.y) REDQ(rv0.z) REDQ(rv0.w)
      REDQ(rv1.x) REDQ(rv1.y) REDQ(rv1.z) REDQ(rv1.w)
      REDQ(rv2.x) REDQ(rv2.y) REDQ(rv2.z) REDQ(rv2.w)
      REDQ(rv3.x) REDQ(rv3.y) REDQ(rv3.z) REDQ(rv3.w)
#undef REDQ
      if (q == 0) {
        atomicAdd(&sm.a.rvacc[0 * 64 + s * 4 + 0], rv0.x);
        atomicAdd(&sm.a.rvacc[0 * 64 + s * 4 + 1], rv0.y);
        atomicAdd(&sm.a.rvacc[0 * 64 + s * 4 + 2], rv0.z);
        atomicAdd(&sm.a.rvacc[0 * 64 + s * 4 + 3], rv0.w);
        atomicAdd(&sm.a.rvacc[1 * 64 + s * 4 + 0], rv1.x);
        atomicAdd(&sm.a.rvacc[1 * 64 + s * 4 + 1], rv1.y);
        atomicAdd(&sm.a.rvacc[1 * 64 + s * 4 + 2], rv1.z);
        atomicAdd(&sm.a.rvacc[1 * 64 + s * 4 + 3], rv1.w);
        atomicAdd(&sm.a.rvacc[2 * 64 + s * 4 + 0], rv2.x);
        atomicAdd(&sm.a.rvacc[2 * 64 + s * 4 + 1], rv2.y);
        atomicAdd(&sm.a.rvacc[2 * 64 + s * 4 + 2], rv2.z);
        atomicAdd(&sm.a.rvacc[2 * 64 + s * 4 + 3], rv2.w);
        atomicAdd(&sm.a.rvacc[3 * 64 + s * 4 + 0], rv3.x);
        atomicAdd(&sm.a.rvacc[3 * 64 + s * 4 + 1], rv3.y);
        atomicAdd(&sm.a.rvacc[3 * 64 + s * 4 + 2], rv3.z);
        atomicAdd(&sm.a.rvacc[3 * 64 + s * 4 + 3], rv3.w);
      }
      __syncthreads();
      if (tid < 4) {
        float ssum = 0.f;
        for (int w8 = 0; w8 < 8; ++w8) ssum += sm.a.wsum[w8 * 4 + tid];
        dp[(b * 4 + tid) * 4 + ch] = ssum;
      }
      if (tid < 256) rvp[(b * 4 + ch) * 256 + tid] = sm.a.rvacc[tid];
    }
    gsync(bar, ++rnd);
  }
}

extern "C" void kernel_launch(void* const* d_in, const int* in_sizes, int n_in,
                              void* d_out, int out_size, void* d_ws, size_t ws_size,
                              hipStream_t stream) {
  const float* x_seq = (const float*)d_in[0];
  const float* Wih = (const float*)d_in[1];
  const float* Whh = (const float*)d_in[2];
  const float* bih = (const float*)d_in[3];
  const float* bhh = (const float*)d_in[4];
  const float* Wout = (const float*)d_in[5];
  const float* bout = (const float*)d_in[6];
  const float* Wkey = (const float*)d_in[7];
  const float* bkey = (const float*)d_in[8];
  const float* alpha = (const float*)d_in[9];
  const float* gamma = (const float*)d_in[10];
  float* out = (float*)d_out;
  char* ws = (char*)d_ws;

  hipMemsetAsync(ws + 38803712, 0, 1024, stream);
  mann_mega<<<256, 512, 0, stream>>>(x_seq, Wih, Whh, bih, bhh, Wout, bout,
                                     Wkey, bkey, alpha, gamma, out, ws);
}

// Round 5
// 11443.494 us; speedup vs baseline: 1.3506x; 1.3506x over previous
//
#include <hip/hip_runtime.h>
#include <hip/hip_bf16.h>

// IN=128, H=512, N=2048, W=64, OUT=128, R=4, T=128, B=64
// gate K=896 (x 0:128 | read_vec 128:384 | h 384:896), gate rows 2048
// Wkb rows: 0..127 = Wout, 128..447 = Wkey (read keys 128..383, write key 384..447)
#define EPSF 1e-8f

typedef __attribute__((ext_vector_type(8))) __bf16 bf8;
typedef __attribute__((ext_vector_type(4))) float f4;

__device__ __forceinline__ short f2bf(float f) {
  union { __hip_bfloat16 b; short s; } u;
  u.b = __float2bfloat16(f);
  return u.s;
}
__device__ __forceinline__ float sigf(float x) { return 1.f / (1.f + __expf(-x)); }
__device__ __forceinline__ float red16(float v) {
  v += __shfl_xor(v, 1); v += __shfl_xor(v, 2);
  v += __shfl_xor(v, 4); v += __shfl_xor(v, 8);
  return v;
}

// Grid barrier, round k=1,2,...
// Arrival: each block stores k to its OWN flag word bar[bid*16] (no contention).
// Check: block 0 wave 0 polls all 256 flags with relaxed LOADS (concurrent at
// LLC, unlike RMWs which serialize ~200ns each — the R3/R4 barrier cost).
// Release: checker stores k to 8 flag lines; pollers use relaxed LOADS.
__device__ __forceinline__ void gsync(unsigned* bar, unsigned k) {
  __syncthreads();
  if (threadIdx.x == 0) {
    __threadfence();
    __hip_atomic_store(&bar[blockIdx.x * 16], k, __ATOMIC_RELAXED,
                       __HIP_MEMORY_SCOPE_AGENT);
  }
  if (blockIdx.x == 0) {
    if (threadIdx.x < 64) {
      const int l = threadIdx.x;
      for (;;) {
        unsigned mn = 0xffffffffu;
#pragma unroll
        for (int j = 0; j < 4; ++j) {
          unsigned v = __hip_atomic_load(&bar[(l * 4 + j) * 16], __ATOMIC_RELAXED,
                                         __HIP_MEMORY_SCOPE_AGENT);
          mn = v < mn ? v : mn;
        }
        if (__all(mn >= k)) break;
        __builtin_amdgcn_s_sleep(1);
      }
      if (l < 8)
        __hip_atomic_store(&bar[4096 + l * 16], k, __ATOMIC_RELAXED,
                           __HIP_MEMORY_SCOPE_AGENT);
    }
  } else if (threadIdx.x == 0) {
    const unsigned g = blockIdx.x >> 5;
    while (__hip_atomic_load(&bar[4096 + g * 16], __ATOMIC_RELAXED,
                             __HIP_MEMORY_SCOPE_AGENT) < k)
      __builtin_amdgcn_s_sleep(2);
  }
  if (threadIdx.x == 0) __threadfence();
  __syncthreads();
}

__global__ __launch_bounds__(512) void mann_mega(
    const float* __restrict__ x_seq, const float* __restrict__ Wih,
    const float* __restrict__ Whh, const float* __restrict__ bih,
    const float* __restrict__ bhh, const float* __restrict__ Wout,
    const float* __restrict__ boutp, const float* __restrict__ Wkey,
    const float* __restrict__ bkeyp, const float* __restrict__ alphap,
    const float* __restrict__ gammap, float* __restrict__ out, char* ws) {
  float* M = (float*)(ws);                     // 33554432
  float* rwb0 = (float*)(ws + 33554432);       // 2097152  exps [b][n][r] f4
  float* rwb1 = (float*)(ws + 35651584);       // 2097152
  float* usage = (float*)(ws + 37748736);      // 524288
  float* cst = (float*)(ws + 38273024);        // 131072
  short* hb0 = (short*)(ws + 38404096);        // 65536
  short* hb1 = (short*)(ws + 38469632);        // 65536
  float* rvp = (float*)(ws + 38535168);        // 262144 rv partials [b][ch][256]
  float* dp = (float*)(ws + 38797312);         // 4096   denom partials [b][r][ch]
  float* sd0 = (float*)(ws + 38801408);        // 1024
  float* sd1 = (float*)(ws + 38802432);        // 1024
  int* lu = (int*)(ws + 38803456);             // 1024
  unsigned* bar = (unsigned*)(ws + 38804480);  // 20480 (host memset 0)
  short* Wc = (short*)(ws + 38824960);         // 3670016
  short* Wkb = (short*)(ws + 42494976);        // 458752 -> end 42953728

  __shared__ union {
    // P1: X panel in MFMA-fragment order: tile(msl,kk) = (msl*28+kk)*512 shorts,
    // within tile lane slot*8 -> MFMA ds_read_b128 is lane-contiguous (no conflicts)
    struct { short Xs[57344]; } g;
    struct { float sv[512]; int si[512]; } m;  // P1 usage argmin
    struct { short hs[512]; float kbuf[256]; float wkbuf[64];
             float rvacc[256]; float wsum[32]; } a;  // PA
  } sm;
  __shared__ float gbuf[64 * 33];
  __shared__ float denl[256];

  const int tid = threadIdx.x;
  const int lane = tid & 63;
  const int wv = tid >> 6;
  const int s = lane & 15;
  const int q = lane >> 4;
  unsigned rnd = 0;

  // ---------------- prologue ----------------
  {
    const unsigned gid = blockIdx.x * 512 + tid;
    const unsigned gs = 256 * 512;
    for (unsigned i = gid; i < 2048u * 896u; i += gs) {
      unsigned row = i / 896u, k = i - row * 896u;
      float v = (k < 384u) ? Wih[row * 384u + k] : Whh[row * 512u + (k - 384u)];
      Wc[i] = f2bf(v);
    }
    for (unsigned i = gid; i < 448u * 512u; i += gs) {
      unsigned row = i >> 9, k = i & 511u;
      float v = (row < 128u) ? Wout[row * 512u + k] : Wkey[(row - 128u) * 512u + k];
      Wkb[i] = f2bf(v);
    }
    for (unsigned i = gid; i < 8388608u; i += gs) M[i] = 1e-6f;
    for (unsigned i = gid; i < 524288u; i += gs) rwb1[i] = 0.f;  // exp_{-1}=0
    for (unsigned i = gid; i < 131072u; i += gs) usage[i] = 0.f;
    if (gid < 32768u) { cst[gid] = 0.f; hb1[gid] = 0; }
    for (unsigned i = gid; i < 65536u; i += gs) rvp[i] = 0.f;
    if (gid < 1024u) dp[gid] = 0.25f;  // denom_{-1}=1 -> rv_{-1}=0
    if (gid < 256u) sd1[gid] = 1.f;    // denom_{-1}=1
    if (gid < 64u) lu[gid] = 0;        // argmin(usage_{-1}=0) = 0
  }
  gsync(bar, ++rnd);

  for (int t = 0; t < 128; ++t) {
    const int p = t & 1;
    short* hN = p ? hb1 : hb0;
    const short* hP = p ? hb0 : hb1;
    float* rwCur = p ? rwb1 : rwb0;       // exps of step t (written in PA)
    const float* rwM1 = p ? rwb0 : rwb1;  // exps of step t-1
    const float* rwM2 = rwCur;            // exps of step t-2 (stale content)
    float* sdM1w = p ? sd0 : sd1;         // denoms of step t-1 (stored this P1)
    const float* sdM1 = sdM1w;
    const float* sdM2 = p ? sd1 : sd0;    // denoms of step t-2

    // ========== P1 phase ==========
    if (blockIdx.x < 64) {
      const int j0 = blockIdx.x * 8;
      if (tid < 256) {
        float d = dp[tid * 4 + 0] + dp[tid * 4 + 1] + dp[tid * 4 + 2] + dp[tid * 4 + 3];
        denl[tid] = 1.f / d;  // inv denom_{t-1}[b*4+r]
      }
      __syncthreads();
      // stage X panel [64 x 896] bf16 in fragment order; thread row = lane
      for (int it = 0; it < 28; ++it) {
        const int row = lane;
        const int k0 = (it * 8 + wv) * 4;
        short4 o;
        if (k0 < 128) {
          float4 v = *(const float4*)&x_seq[((size_t)t * 64 + row) * 128 + k0];
          o.x = f2bf(v.x); o.y = f2bf(v.y); o.z = f2bf(v.z); o.w = f2bf(v.w);
        } else if (k0 < 384) {
          int col = k0 - 128;
          float iv = denl[row * 4 + (col >> 6)];
          float a0 = 0, a1 = 0, a2 = 0, a3 = 0;
#pragma unroll
          for (int cc = 0; cc < 4; ++cc) {
            float4 v = *(const float4*)&rvp[(row * 4 + cc) * 256 + col];
            a0 += v.x; a1 += v.y; a2 += v.z; a3 += v.w;
          }
          o.x = f2bf(a0 * iv); o.y = f2bf(a1 * iv);
          o.z = f2bf(a2 * iv); o.w = f2bf(a3 * iv);
        } else {
          o = *(const short4*)&hP[row * 512 + (k0 - 384)];
        }
        int tile = (row >> 4) * 28 + (k0 >> 5);
        int slot = (row & 15) + 16 * ((k0 >> 3) & 3);
        *(short4*)&sm.g.Xs[tile * 512 + slot * 8 + (k0 & 7)] = o;
      }
      __syncthreads();
      // MFMA: 8 waves = 4 m-slices x 2 n-halves; B-operand direct from L2
      {
        const int msl = wv >> 1, nh = wv & 1;
        const int rr = nh * 16 + s;
        const int gg = rr >> 3, jj = rr & 7;
        const size_t wrow = (size_t)(gg * 512 + j0 + jj) * 896;
        f4 acc = {0.f, 0.f, 0.f, 0.f};
#pragma unroll
        for (int kk = 0; kk < 28; ++kk) {
          bf8 a = *(const bf8*)&sm.g.Xs[((msl * 28 + kk) * 64 + lane) * 8];
          bf8 b = *(const bf8*)&Wc[wrow + kk * 32 + q * 8];
          acc = __builtin_amdgcn_mfma_f32_16x16x32_bf16(a, b, acc, 0, 0, 0);
        }
#pragma unroll
        for (int reg = 0; reg < 4; ++reg) {
          int bat = msl * 16 + q * 4 + reg;
          gbuf[bat * 33 + rr] = acc[reg];
        }
      }
      __syncthreads();
      {
        int b = tid & 63, jj = tid >> 6, j = j0 + jj;
        float gi = gbuf[b * 33 + jj] + bih[j] + bhh[j];
        float gf = gbuf[b * 33 + 8 + jj] + bih[512 + j] + bhh[512 + j];
        float gg2 = gbuf[b * 33 + 16 + jj] + bih[1024 + j] + bhh[1024 + j];
        float go = gbuf[b * 33 + 24 + jj] + bih[1536 + j] + bhh[1536 + j];
        float co = cst[b * 512 + j];
        float cn = sigf(gf) * co + sigf(gi) * tanhf(gg2);
        float hn = sigf(go) * tanhf(cn);
        cst[b * 512 + j] = cn;
        hN[b * 512 + j] = f2bf(hn);
      }
    } else if (blockIdx.x < 128 && t > 0) {
      // finalize step t-1: denoms -> sd, usage update, argmin -> lu_t
      const int b = blockIdx.x - 64;
      float idenC[4], idenO[4];
#pragma unroll
      for (int r = 0; r < 4; ++r) {
        float d = dp[(b * 4 + r) * 4 + 0] + dp[(b * 4 + r) * 4 + 1] +
                  dp[(b * 4 + r) * 4 + 2] + dp[(b * 4 + r) * 4 + 3];
        idenC[r] = 1.f / d;
        if (tid == 0) sdM1w[b * 4 + r] = d;
        idenO[r] = 1.f / sdM2[b * 4 + r];
      }
      const float sa = sigf(alphap[0]);
      const float ga = gammap[0];
      const int luB = lu[b];
      float vm = INFINITY;
      int im = 0x7fffffff;
      for (int i = 0; i < 4; ++i) {
        int n = i * 512 + tid;
        float4 eC = *(const float4*)&rwM1[((size_t)b * 2048 + n) * 4];
        float4 eO = *(const float4*)&rwM2[((size_t)b * 2048 + n) * 4];
        float wps = eO.x * idenO[0] + eO.y * idenO[1] + eO.z * idenO[2] + eO.w * idenO[3];
        float ww = sa * wps + (1.f - sa) * ((n == luB) ? 1.f : 0.f);
        float sn = eC.x * idenC[0] + eC.y * idenC[1] + eC.z * idenC[2] + eC.w * idenC[3];
        float u = ga * usage[b * 2048 + n] + sn + ww;
        usage[b * 2048 + n] = u;
        if (u < vm) { vm = u; im = n; }
      }
      sm.m.sv[tid] = vm; sm.m.si[tid] = im;
      __syncthreads();
      for (int off = 256; off > 0; off >>= 1) {
        if (tid < off) {
          float v2 = sm.m.sv[tid + off]; int j2 = sm.m.si[tid + off];
          if (v2 < sm.m.sv[tid] || (v2 == sm.m.sv[tid] && j2 < sm.m.si[tid])) {
            sm.m.sv[tid] = v2; sm.m.si[tid] = j2;
          }
        }
        __syncthreads();
      }
      if (tid == 0) lu[b] = sm.m.si[0];
    }
    gsync(bar, ++rnd);

    // ========== PA phase: keys/out + single fused M-pass ==========
    {
      const int b = blockIdx.x >> 2, ch = blockIdx.x & 3;
      if (tid < 128) *(short4*)&sm.a.hs[tid * 4] = *(const short4*)&hN[b * 512 + tid * 4];
      if (tid < 256) sm.a.rvacc[tid] = 0.f;
      __syncthreads();
      // keys (redundant per block) + out slice: 352 rows = 11 passes x 32
      for (int pp = 0; pp < 11; ++pp) {
        int idx = pp * 32 + wv * 4 + q;
        int wr; float bias;
        if (idx < 320) { wr = 128 + idx; bias = bkeyp[idx]; }
        else { wr = ch * 32 + (idx - 320); bias = boutp[wr]; }
        float acc = 0.f;
#pragma unroll
        for (int i = 0; i < 4; ++i) {
          bf8 w8 = *(const bf8*)&Wkb[(size_t)wr * 512 + i * 128 + s * 8];
          bf8 h8 = *(const bf8*)&sm.a.hs[i * 128 + s * 8];
#pragma unroll
          for (int j = 0; j < 8; ++j) acc += (float)w8[j] * (float)h8[j];
        }
        acc = red16(acc) + bias;
        if (s == 0) {
          if (idx < 256) sm.a.kbuf[idx] = acc;
          else if (idx < 320) sm.a.wkbuf[idx - 256] = acc;
          else out[((size_t)t * 64 + b) * 128 + wr] = acc;
        }
      }
      __syncthreads();
      float4 kn[4];
#pragma unroll
      for (int r = 0; r < 4; ++r) {
        float4 k4 = *(float4*)&sm.a.kbuf[r * 64 + s * 4];
        float ss = k4.x * k4.x + k4.y * k4.y + k4.z * k4.z + k4.w * k4.w;
        ss = red16(ss);
        float iv = 1.f / (sqrtf(ss) + EPSF);
        kn[r].x = k4.x * iv; kn[r].y = k4.y * iv;
        kn[r].z = k4.z * iv; kn[r].w = k4.w * iv;
      }
      const float4 wk = *(float4*)&sm.a.wkbuf[s * 4];
      float ipd[4];
#pragma unroll
      for (int r = 0; r < 4; ++r) ipd[r] = 1.f / sdM1[b * 4 + r];
      const float sa = sigf(alphap[0]);
      const int luB = lu[b];
      float4* M4 = (float4*)M;
      float4 rv0 = {0,0,0,0}, rv1 = {0,0,0,0}, rv2 = {0,0,0,0}, rv3 = {0,0,0,0};
      float es0 = 0.f, es1 = 0.f, es2 = 0.f, es3 = 0.f;
      for (int i = 0; i < 16; ++i) {
        const int n = ch * 512 + wv * 64 + i * 4 + q;
        const size_t mi = ((size_t)b * 2048 + n) * 16 + s;
        float4 m4 = M4[mi];
        float4 ep = *(const float4*)&rwM1[((size_t)b * 2048 + n) * 4];
        float ssm = m4.x * m4.x + m4.y * m4.y + m4.z * m4.z + m4.w * m4.w;
        float d0 = m4.x * kn[0].x + m4.y * kn[0].y + m4.z * kn[0].z + m4.w * kn[0].w;
        float d1 = m4.x * kn[1].x + m4.y * kn[1].y + m4.z * kn[1].z + m4.w * kn[1].w;
        float d2 = m4.x * kn[2].x + m4.y * kn[2].y + m4.z * kn[2].z + m4.w * kn[2].w;
        float d3 = m4.x * kn[3].x + m4.y * kn[3].y + m4.z * kn[3].z + m4.w * kn[3].w;
        ssm = red16(ssm);
        d0 = red16(d0); d1 = red16(d1); d2 = red16(d2); d3 = red16(d3);
        float iv = 1.f / (sqrtf(ssm) + EPSF);
        float e0 = __expf(d0 * iv), e1 = __expf(d1 * iv);
        float e2 = __expf(d2 * iv), e3 = __expf(d3 * iv);
        rv0.x += e0 * m4.x; rv0.y += e0 * m4.y; rv0.z += e0 * m4.z; rv0.w += e0 * m4.w;
        rv1.x += e1 * m4.x; rv1.y += e1 * m4.y; rv1.z += e1 * m4.z; rv1.w += e1 * m4.w;
        rv2.x += e2 * m4.x; rv2.y += e2 * m4.y; rv2.z += e2 * m4.z; rv2.w += e2 * m4.w;
        rv3.x += e3 * m4.x; rv3.y += e3 * m4.y; rv3.z += e3 * m4.z; rv3.w += e3 * m4.w;
        if (s == 0) {
          float4 ev; ev.x = e0; ev.y = e1; ev.z = e2; ev.w = e3;
          *(float4*)&rwCur[((size_t)b * 2048 + n) * 4] = ev;
          es0 += e0; es1 += e1; es2 += e2; es3 += e3;
        }
        float wps = ep.x * ipd[0] + ep.y * ipd[1] + ep.z * ipd[2] + ep.w * ipd[3];
        float onehot = (n == luB) ? 1.f : 0.f;
        float ww = sa * wps + (1.f - sa) * onehot;
        float keep = 1.f - onehot;
        float4 mn;
        mn.x = m4.x * keep + ww * wk.x;
        mn.y = m4.y * keep + ww * wk.y;
        mn.z = m4.z * keep + ww * wk.z;
        mn.w = m4.w * keep + ww * wk.w;
        M4[mi] = mn;
      }
      es0 += __shfl_xor(es0, 16); es0 += __shfl_xor(es0, 32);
      es1 += __shfl_xor(es1, 16); es1 += __shfl_xor(es1, 32);
      es2 += __shfl_xor(es2, 16); es2 += __shfl_xor(es2, 32);
      es3 += __shfl_xor(es3, 16); es3 += __shfl_xor(es3, 32);
      if (lane == 0) {
        sm.a.wsum[wv * 4 + 0] = es0; sm.a.wsum[wv * 4 + 1] = es1;
        sm.a.wsum[wv * 4 + 2] = es2; sm.a.wsum[wv * 4 + 3] = es3;
      }
#define REDQ(v) { v += __shfl_xor(v, 16); v += __shfl_xor(v, 32); }
      REDQ(rv0.x) REDQ(rv0.y) REDQ(rv0.z) REDQ(rv0.w)
      REDQ(rv1.x) REDQ(rv1.y) REDQ(rv1.z) REDQ(rv1.w)
      REDQ(rv2.x) REDQ(rv2.y) REDQ(rv2.z) REDQ(rv2.w)
      REDQ(rv3.x) REDQ(rv3.y) REDQ(rv3.z) REDQ(rv3.w)
#undef REDQ
      if (q == 0) {
        atomicAdd(&sm.a.rvacc[0 * 64 + s * 4 + 0], rv0.x);
        atomicAdd(&sm.a.rvacc[0 * 64 + s * 4 + 1], rv0.y);
        atomicAdd(&sm.a.rvacc[0 * 64 + s * 4 + 2], rv0.z);
        atomicAdd(&sm.a.rvacc[0 * 64 + s * 4 + 3], rv0.w);
        atomicAdd(&sm.a.rvacc[1 * 64 + s * 4 + 0], rv1.x);
        atomicAdd(&sm.a.rvacc[1 * 64 + s * 4 + 1], rv1.y);
        atomicAdd(&sm.a.rvacc[1 * 64 + s * 4 + 2], rv1.z);
        atomicAdd(&sm.a.rvacc[1 * 64 + s * 4 + 3], rv1.w);
        atomicAdd(&sm.a.rvacc[2 * 64 + s * 4 + 0], rv2.x);
        atomicAdd(&sm.a.rvacc[2 * 64 + s * 4 + 1], rv2.y);
        atomicAdd(&sm.a.rvacc[2 * 64 + s * 4 + 2], rv2.z);
        atomicAdd(&sm.a.rvacc[2 * 64 + s * 4 + 3], rv2.w);
        atomicAdd(&sm.a.rvacc[3 * 64 + s * 4 + 0], rv3.x);
        atomicAdd(&sm.a.rvacc[3 * 64 + s * 4 + 1], rv3.y);
        atomicAdd(&sm.a.rvacc[3 * 64 + s * 4 + 2], rv3.z);
        atomicAdd(&sm.a.rvacc[3 * 64 + s * 4 + 3], rv3.w);
      }
      __syncthreads();
      if (tid < 4) {
        float ssum = 0.f;
        for (int w8 = 0; w8 < 8; ++w8) ssum += sm.a.wsum[w8 * 4 + tid];
        dp[(b * 4 + tid) * 4 + ch] = ssum;
      }
      if (tid < 256) rvp[(b * 4 + ch) * 256 + tid] = sm.a.rvacc[tid];
    }
    gsync(bar, ++rnd);
  }
}

extern "C" void kernel_launch(void* const* d_in, const int* in_sizes, int n_in,
                              void* d_out, int out_size, void* d_ws, size_t ws_size,
                              hipStream_t stream) {
  const float* x_seq = (const float*)d_in[0];
  const float* Wih = (const float*)d_in[1];
  const float* Whh = (const float*)d_in[2];
  const float* bih = (const float*)d_in[3];
  const float* bhh = (const float*)d_in[4];
  const float* Wout = (const float*)d_in[5];
  const float* bout = (const float*)d_in[6];
  const float* Wkey = (const float*)d_in[7];
  const float* bkey = (const float*)d_in[8];
  const float* alpha = (const float*)d_in[9];
  const float* gamma = (const float*)d_in[10];
  float* out = (float*)d_out;
  char* ws = (char*)d_ws;

  // zero the barrier flag region (ws is re-poisoned before every call)
  hipMemsetAsync(ws + 38804480, 0, 20480, stream);
  mann_mega<<<256, 512, 0, stream>>>(x_seq, Wih, Whh, bih, bhh, Wout, bout,
                                     Wkey, bkey, alpha, gamma, out, ws);
}

// Round 6
// 8522.587 us; speedup vs baseline: 1.8135x; 1.3427x over previous
//
#include <hip/hip_runtime.h>
#include <hip/hip_bf16.h>

// IN=128, H=512, N=2048, W=64, OUT=128, R=4, T=128, B=64
// gate K=896 (x 0:128 | read_vec 128:384 | h 384:896), gate rows 2048
// Wkb rows: 0..127 = Wout, 128..447 = Wkey (read keys 128..383, write key 384..447)
//
// Coherence model (gfx950, non-coherent per-XCD L2s, NO fences anywhere):
//  - block-private data (M, usage, cst, own rw range via LDS): normal cached.
//    Persistent kernel => blocks never migrate => private L2 lines never stale.
//  - cross-block data: writers use sc0 sc1 write-through stores (visible at
//    MALL), readers use sc0 sc1 loads (bypass own L2). read_vec is reduced
//    with device-scope atomicAdd (executes at MALL).
//  - ordering: every thread executes s_waitcnt vmcnt(0) entering gsync, so all
//    sc1 stores/atomics are globally visible before the arrival flag.
#define EPSF 1e-8f

typedef __attribute__((ext_vector_type(8))) __bf16 bf8;
typedef __attribute__((ext_vector_type(4))) float f4;
typedef __attribute__((ext_vector_type(2))) unsigned u2;

union S4U2 { short4 s; u2 u; };

__device__ __forceinline__ short f2bf(float f) {
  union { __hip_bfloat16 b; short s; } u;
  u.b = __float2bfloat16(f);
  return u.s;
}
__device__ __forceinline__ float sigf(float x) { return 1.f / (1.f + __expf(-x)); }
__device__ __forceinline__ float red16(float v) {
  v += __shfl_xor(v, 1); v += __shfl_xor(v, 2);
  v += __shfl_xor(v, 4); v += __shfl_xor(v, 8);
  return v;
}

// ---- coherent access helpers (write-through / L2-bypass) ----
__device__ __forceinline__ void st_coh16(void* p, f4 v) {
  asm volatile("global_store_dwordx4 %0, %1, off sc0 sc1" :: "v"(p), "v"(v) : "memory");
}
__device__ __forceinline__ void st_coh8(void* p, u2 v) {
  asm volatile("global_store_dwordx2 %0, %1, off sc0 sc1" :: "v"(p), "v"(v) : "memory");
}
__device__ __forceinline__ void st_coh4(void* p, float v) {
  asm volatile("global_store_dword %0, %1, off sc0 sc1" :: "v"(p), "v"(v) : "memory");
}
__device__ __forceinline__ void st_coh4u(void* p, unsigned v) {
  asm volatile("global_store_dword %0, %1, off sc0 sc1" :: "v"(p), "v"(v) : "memory");
}
__device__ __forceinline__ void st_coh2(void* p, unsigned v) {
  asm volatile("global_store_short %0, %1, off sc0 sc1" :: "v"(p), "v"(v) : "memory");
}

#define LD8X4(v0,v1,v2,v3,v4,v5,v6,v7,p0,p1,p2,p3,p4,p5,p6,p7) \
  asm volatile( \
    "global_load_dwordx4 %0, %8, off sc0 sc1\n\t" \
    "global_load_dwordx4 %1, %9, off sc0 sc1\n\t" \
    "global_load_dwordx4 %2, %10, off sc0 sc1\n\t" \
    "global_load_dwordx4 %3, %11, off sc0 sc1\n\t" \
    "global_load_dwordx4 %4, %12, off sc0 sc1\n\t" \
    "global_load_dwordx4 %5, %13, off sc0 sc1\n\t" \
    "global_load_dwordx4 %6, %14, off sc0 sc1\n\t" \
    "global_load_dwordx4 %7, %15, off sc0 sc1\n\t" \
    "s_waitcnt vmcnt(0)" \
    : "=&v"(v0),"=&v"(v1),"=&v"(v2),"=&v"(v3),"=&v"(v4),"=&v"(v5),"=&v"(v6),"=&v"(v7) \
    : "v"(p0),"v"(p1),"v"(p2),"v"(p3),"v"(p4),"v"(p5),"v"(p6),"v"(p7) : "memory")

#define LD8X2(v0,v1,v2,v3,v4,v5,v6,v7,p0,p1,p2,p3,p4,p5,p6,p7) \
  asm volatile( \
    "global_load_dwordx2 %0, %8, off sc0 sc1\n\t" \
    "global_load_dwordx2 %1, %9, off sc0 sc1\n\t" \
    "global_load_dwordx2 %2, %10, off sc0 sc1\n\t" \
    "global_load_dwordx2 %3, %11, off sc0 sc1\n\t" \
    "global_load_dwordx2 %4, %12, off sc0 sc1\n\t" \
    "global_load_dwordx2 %5, %13, off sc0 sc1\n\t" \
    "global_load_dwordx2 %6, %14, off sc0 sc1\n\t" \
    "global_load_dwordx2 %7, %15, off sc0 sc1\n\t" \
    "s_waitcnt vmcnt(0)" \
    : "=&v"(v0),"=&v"(v1),"=&v"(v2),"=&v"(v3),"=&v"(v4),"=&v"(v5),"=&v"(v6),"=&v"(v7) \
    : "v"(p0),"v"(p1),"v"(p2),"v"(p3),"v"(p4),"v"(p5),"v"(p6),"v"(p7) : "memory")

// Grid barrier, round k=1,2,... No fences: per-block own-flag arrival stores,
// checker block 255 (idle in P1 phase) polls with coherent loads, releases 8
// group lines. All threads waitcnt their own wave's vmem first.
__device__ __forceinline__ void gsync(unsigned* bar, unsigned k) {
  asm volatile("s_waitcnt vmcnt(0)" ::: "memory");
  __syncthreads();
  if (threadIdx.x == 0)
    __hip_atomic_store(&bar[blockIdx.x * 16], k, __ATOMIC_RELAXED,
                       __HIP_MEMORY_SCOPE_AGENT);
  if (blockIdx.x == 255) {
    if (threadIdx.x < 64) {
      const int l = threadIdx.x;
      for (;;) {
        unsigned mn = 0xffffffffu;
#pragma unroll
        for (int j = 0; j < 4; ++j) {
          unsigned v = __hip_atomic_load(&bar[(l * 4 + j) * 16], __ATOMIC_RELAXED,
                                         __HIP_MEMORY_SCOPE_AGENT);
          mn = v < mn ? v : mn;
        }
        if (__all(mn >= k)) break;
        __builtin_amdgcn_s_sleep(1);
      }
      if (l < 8)
        __hip_atomic_store(&bar[4096 + l * 16], k, __ATOMIC_RELAXED,
                           __HIP_MEMORY_SCOPE_AGENT);
    }
  } else if (threadIdx.x == 0) {
    const unsigned g = blockIdx.x >> 5;
    while (__hip_atomic_load(&bar[4096 + g * 16], __ATOMIC_RELAXED,
                             __HIP_MEMORY_SCOPE_AGENT) < k)
      __builtin_amdgcn_s_sleep(1);
  }
  __syncthreads();
}

__global__ __launch_bounds__(512, 2) void mann_mega(
    const float* __restrict__ x_seq, const float* __restrict__ Wih,
    const float* __restrict__ Whh, const float* __restrict__ bih,
    const float* __restrict__ bhh, const float* __restrict__ Wout,
    const float* __restrict__ boutp, const float* __restrict__ Wkey,
    const float* __restrict__ bkeyp, const float* __restrict__ alphap,
    const float* __restrict__ gammap, float* __restrict__ out, char* ws) {
  float* M = (float*)(ws);                     // 33554432  private per PA block
  float* rwb0 = (float*)(ws + 33554432);       // 2097152   exps [b][n][r], sc1
  float* rwb1 = (float*)(ws + 35651584);       // 2097152
  float* usage = (float*)(ws + 37748736);      // 524288    private (finalize)
  float* cst = (float*)(ws + 38273024);        // 131072    private (gates)
  short* hb0 = (short*)(ws + 38404096);        // 65536     sc1/coh
  short* hb1 = (short*)(ws + 38469632);        // 65536
  float* rv0 = (float*)(ws + 38535168);        // 65536     atomic-reduced rv
  float* rv1 = (float*)(ws + 38600704);        // 65536
  float* dp = (float*)(ws + 38666240);         // 4096      denom partials
  float* sd0 = (float*)(ws + 38670336);        // 1024      denoms [b][r]
  float* sd1 = (float*)(ws + 38671360);        // 1024
  unsigned* lu = (unsigned*)(ws + 38672384);   // 1024
  unsigned* bar = (unsigned*)(ws + 38673408);  // 20480 (host memset 0)
  short* Wc = (short*)(ws + 38693888);         // 3670016
  short* Wkb = (short*)(ws + 42363904);        // 458752 -> end 42822656

  __shared__ union {
    struct { short Xs[57344]; } g;             // P1 X panel, MFMA fragment order
    struct { float sv[512]; int si[512]; } m;  // finalize argmin
    struct { short hs[512]; float kbuf[256]; float wkbuf[64];
             float rvacc[256]; float wsum[32]; } a;  // PA
  } sm;
  __shared__ float gbuf[64 * 33];
  __shared__ float denl[256];
  __shared__ float rwPrev[2048];  // this PA block's own exps of step t-1 (persists)

  const int tid = threadIdx.x;
  const int lane = tid & 63;
  const int wv = tid >> 6;
  const int s = lane & 15;
  const int q = lane >> 4;
  unsigned rnd = 0;

  // ---------------- prologue: weight conversion only (sc1 stores) ----------------
  {
    const unsigned gid = blockIdx.x * 512 + tid;
    const unsigned gs = 256 * 512;
    for (unsigned i4 = gid; i4 < 458752u; i4 += gs) {  // Wc: 2048x896 shorts
      unsigned e = i4 * 4;
      unsigned row = e / 896u, k = e - row * 896u;
      float4 v = (k < 384u) ? *(const float4*)&Wih[row * 384u + k]
                            : *(const float4*)&Whh[row * 512u + (k - 384u)];
      S4U2 o;
      o.s.x = f2bf(v.x); o.s.y = f2bf(v.y); o.s.z = f2bf(v.z); o.s.w = f2bf(v.w);
      st_coh8(Wc + e, o.u);
    }
    for (unsigned i4 = gid; i4 < 57344u; i4 += gs) {  // Wkb: 448x512 shorts
      unsigned e = i4 * 4;
      unsigned row = e >> 9, k = e & 511u;
      float4 v = (row < 128u) ? *(const float4*)&Wout[row * 512u + k]
                              : *(const float4*)&Wkey[(row - 128u) * 512u + k];
      S4U2 o;
      o.s.x = f2bf(v.x); o.s.y = f2bf(v.y); o.s.z = f2bf(v.z); o.s.w = f2bf(v.w);
      st_coh8(Wkb + e, o.u);
    }
  }
  gsync(bar, ++rnd);

  for (int t = 0; t < 128; ++t) {
    const int p = t & 1;
    short* hN = p ? hb1 : hb0;
    const short* hP = p ? hb0 : hb1;
    float* rwCur = p ? rwb1 : rwb0;       // exps of step t (sc1 in PA)
    const float* rwM1 = p ? rwb0 : rwb1;  // exps of step t-1
    const float* rwM2 = rwCur;            // exps of step t-2 (stale buffer)
    float* sdW = p ? sd1 : sd0;           // denom_{t-1}, written by finalize_t
    const float* sdM2 = p ? sd0 : sd1;    // denom_{t-2}
    float* rvW = p ? rv1 : rv0;           // atomic target of PA_t
    const float* rvR = p ? rv0 : rv1;     // reduced rv of step t-1

    // ========== P1 phase ==========
    if (blockIdx.x < 64) {
      // ---- gates GEMM + LSTM cell ----
      const int j0 = blockIdx.x * 8;
      if (tid < 256) {
        float iv = 1.f;
        if (t > 0) {
          f4 d4;
          asm volatile("global_load_dwordx4 %0, %1, off sc0 sc1\n\ts_waitcnt vmcnt(0)"
                       : "=&v"(d4) : "v"((const void*)(dp + tid * 4)) : "memory");
          iv = 1.f / (d4.x + d4.y + d4.z + d4.w);
        }
        denl[tid] = iv;  // 1/denom_{t-1}[b*4+r]
      }
      __syncthreads();
      // stage X panel [64 x 896] bf16 in MFMA-fragment order; thread row = lane
      // section 1: x_seq, it=0..3 (k0 in [0,128)), normal cached loads
      {
        const int row = lane;
#pragma unroll
        for (int it = 0; it < 4; ++it) {
          int k0 = (it * 8 + wv) * 4;
          float4 v = *(const float4*)&x_seq[((size_t)t * 64 + row) * 128 + k0];
          short4 o;
          o.x = f2bf(v.x); o.y = f2bf(v.y); o.z = f2bf(v.z); o.w = f2bf(v.w);
          int tile = (row >> 4) * 28 + (k0 >> 5);
          int slot = (row & 15) + 16 * ((k0 >> 3) & 3);
          *(short4*)&sm.g.Xs[tile * 512 + slot * 8 + (k0 & 7)] = o;
        }
        // section 2: read_vec = rvR/denom, it=4..11 (k0 in [128,384)), coherent
        if (t > 0) {
          f4 rvv[8];
          const void* pp[8];
#pragma unroll
          for (int j = 0; j < 8; ++j) {
            int k0 = ((4 + j) * 8 + wv) * 4;
            pp[j] = (const void*)(rvR + row * 256 + (k0 - 128));
          }
          LD8X4(rvv[0], rvv[1], rvv[2], rvv[3], rvv[4], rvv[5], rvv[6], rvv[7],
                pp[0], pp[1], pp[2], pp[3], pp[4], pp[5], pp[6], pp[7]);
#pragma unroll
          for (int j = 0; j < 8; ++j) {
            int k0 = ((4 + j) * 8 + wv) * 4;
            int col = k0 - 128;
            float iv = denl[row * 4 + (col >> 6)];
            short4 o;
            o.x = f2bf(rvv[j].x * iv); o.y = f2bf(rvv[j].y * iv);
            o.z = f2bf(rvv[j].z * iv); o.w = f2bf(rvv[j].w * iv);
            int tile = (row >> 4) * 28 + (k0 >> 5);
            int slot = (row & 15) + 16 * ((k0 >> 3) & 3);
            *(short4*)&sm.g.Xs[tile * 512 + slot * 8 + (k0 & 7)] = o;
          }
          // section 3: h_{t-1}, it=12..27 (k0 in [384,896)), coherent
          u2 hv[16];
          const void* hp[16];
#pragma unroll
          for (int j = 0; j < 16; ++j) {
            int k0 = ((12 + j) * 8 + wv) * 4;
            hp[j] = (const void*)(hP + row * 512 + (k0 - 384));
          }
          LD8X2(hv[0], hv[1], hv[2], hv[3], hv[4], hv[5], hv[6], hv[7],
                hp[0], hp[1], hp[2], hp[3], hp[4], hp[5], hp[6], hp[7]);
          LD8X2(hv[8], hv[9], hv[10], hv[11], hv[12], hv[13], hv[14], hv[15],
                hp[8], hp[9], hp[10], hp[11], hp[12], hp[13], hp[14], hp[15]);
#pragma unroll
          for (int j = 0; j < 16; ++j) {
            int k0 = ((12 + j) * 8 + wv) * 4;
            int tile = (row >> 4) * 28 + (k0 >> 5);
            int slot = (row & 15) + 16 * ((k0 >> 3) & 3);
            *(u2*)&sm.g.Xs[tile * 512 + slot * 8 + (k0 & 7)] = hv[j];
          }
        } else {
          u2 z; z.x = 0; z.y = 0;
#pragma unroll
          for (int j = 0; j < 24; ++j) {
            int k0 = ((4 + j) * 8 + wv) * 4;
            int tile = (row >> 4) * 28 + (k0 >> 5);
            int slot = (row & 15) + 16 * ((k0 >> 3) & 3);
            *(u2*)&sm.g.Xs[tile * 512 + slot * 8 + (k0 & 7)] = z;
          }
        }
      }
      __syncthreads();
      // MFMA: 8 waves = 4 m-slices x 2 n-halves; B-operand normal (L2-resident)
      {
        const int msl = wv >> 1, nh = wv & 1;
        const int rr = nh * 16 + s;
        const int gg = rr >> 3, jj = rr & 7;
        const size_t wrow = (size_t)(gg * 512 + j0 + jj) * 896;
        f4 acc = {0.f, 0.f, 0.f, 0.f};
#pragma unroll
        for (int kk = 0; kk < 28; ++kk) {
          bf8 a = *(const bf8*)&sm.g.Xs[((msl * 28 + kk) * 64 + lane) * 8];
          bf8 b = *(const bf8*)&Wc[wrow + kk * 32 + q * 8];
          acc = __builtin_amdgcn_mfma_f32_16x16x32_bf16(a, b, acc, 0, 0, 0);
        }
#pragma unroll
        for (int reg = 0; reg < 4; ++reg) {
          int bat = msl * 16 + q * 4 + reg;
          gbuf[bat * 33 + rr] = acc[reg];
        }
      }
      __syncthreads();
      {
        int b = tid >> 3, jj = tid & 7, j = j0 + jj;
        float gi = gbuf[b * 33 + jj] + bih[j] + bhh[j];
        float gf = gbuf[b * 33 + 8 + jj] + bih[512 + j] + bhh[512 + j];
        float gg2 = gbuf[b * 33 + 16 + jj] + bih[1024 + j] + bhh[1024 + j];
        float go = gbuf[b * 33 + 24 + jj] + bih[1536 + j] + bhh[1536 + j];
        float co = (t == 0) ? 0.f : cst[b * 512 + j];  // private normal
        float cn = sigf(gf) * co + sigf(gi) * tanhf(gg2);
        float hn = sigf(go) * tanhf(cn);
        cst[b * 512 + j] = cn;
        union { __hip_bfloat16 b16; unsigned short us; } hu;
        hu.b16 = __float2bfloat16(hn);
        st_coh2(hN + b * 512 + j, (unsigned)hu.us);
      }
    } else if (blockIdx.x < 128) {
      // ---- finalize step t-1: denoms -> sdW, usage update, argmin -> lu ----
      if (t > 0) {
        const int b = blockIdx.x - 64;
        f4 dp0, dp1, dp2, dp3, sm2;
        unsigned luv;
        asm volatile(
            "global_load_dwordx4 %0, %6, off sc0 sc1\n\t"
            "global_load_dwordx4 %1, %7, off sc0 sc1\n\t"
            "global_load_dwordx4 %2, %8, off sc0 sc1\n\t"
            "global_load_dwordx4 %3, %9, off sc0 sc1\n\t"
            "global_load_dwordx4 %4, %10, off sc0 sc1\n\t"
            "global_load_dword %5, %11, off sc0 sc1\n\t"
            "s_waitcnt vmcnt(0)"
            : "=&v"(dp0), "=&v"(dp1), "=&v"(dp2), "=&v"(dp3), "=&v"(sm2), "=&v"(luv)
            : "v"((const void*)(dp + (b * 4 + 0) * 4)),
              "v"((const void*)(dp + (b * 4 + 1) * 4)),
              "v"((const void*)(dp + (b * 4 + 2) * 4)),
              "v"((const void*)(dp + (b * 4 + 3) * 4)),
              "v"((const void*)(sdM2 + b * 4)), "v"((const void*)(lu + b))
            : "memory");
        float d0 = dp0.x + dp0.y + dp0.z + dp0.w;
        float d1 = dp1.x + dp1.y + dp1.z + dp1.w;
        float d2 = dp2.x + dp2.y + dp2.z + dp2.w;
        float d3 = dp3.x + dp3.y + dp3.z + dp3.w;
        if (tid == 0) { f4 dv = {d0, d1, d2, d3}; st_coh16(sdW + b * 4, dv); }
        float iC0 = 1.f / d0, iC1 = 1.f / d1, iC2 = 1.f / d2, iC3 = 1.f / d3;
        float iO0 = 0, iO1 = 0, iO2 = 0, iO3 = 0;
        if (t > 1) { iO0 = 1.f / sm2.x; iO1 = 1.f / sm2.y; iO2 = 1.f / sm2.z; iO3 = 1.f / sm2.w; }
        const float sa = sigf(alphap[0]);
        const float ga = gammap[0];
        const int luB = (int)luv;
        f4 ec[4], eo[4];
        {
          const void* pc[4]; const void* po[4];
#pragma unroll
          for (int i = 0; i < 4; ++i) {
            int n = i * 512 + tid;
            pc[i] = (const void*)(rwM1 + ((size_t)b * 2048 + n) * 4);
            po[i] = (const void*)(rwM2 + ((size_t)b * 2048 + n) * 4);
          }
          LD8X4(ec[0], ec[1], ec[2], ec[3], eo[0], eo[1], eo[2], eo[3],
                pc[0], pc[1], pc[2], pc[3], po[0], po[1], po[2], po[3]);
        }
        float vm = INFINITY;
        int im = 0x7fffffff;
#pragma unroll
        for (int i = 0; i < 4; ++i) {
          int n = i * 512 + tid;
          float wps = (t > 1) ? (eo[i].x * iO0 + eo[i].y * iO1 + eo[i].z * iO2 + eo[i].w * iO3)
                              : 0.f;
          float ww = sa * wps + (1.f - sa) * ((n == luB) ? 1.f : 0.f);
          float sn = ec[i].x * iC0 + ec[i].y * iC1 + ec[i].z * iC2 + ec[i].w * iC3;
          float uo = (t == 1) ? 0.f : usage[b * 2048 + n];  // private normal
          float u = ga * uo + sn + ww;
          usage[b * 2048 + n] = u;
          if (u < vm) { vm = u; im = n; }  // n strictly increasing per thread
        }
        sm.m.sv[tid] = vm; sm.m.si[tid] = im;
        __syncthreads();
        for (int off = 256; off > 0; off >>= 1) {
          if (tid < off) {
            float v2 = sm.m.sv[tid + off]; int j2 = sm.m.si[tid + off];
            if (v2 < sm.m.sv[tid] || (v2 == sm.m.sv[tid] && j2 < sm.m.si[tid])) {
              sm.m.sv[tid] = v2; sm.m.si[tid] = j2;
            }
          }
          __syncthreads();
        }
        if (tid == 0) st_coh4u(lu + b, (unsigned)sm.m.si[0]);
      }
    } else if (blockIdx.x < 192) {
      // ---- zero rvW for PA_t's atomics ----
      const int bz = blockIdx.x - 128;
      if (tid < 64) { f4 z = {0, 0, 0, 0}; st_coh16(rvW + bz * 256 + tid * 4, z); }
    }
    gsync(bar, ++rnd);

    // ========== PA phase: keys/out + single fused M-pass (all 256 blocks) ==========
    {
      const int b = blockIdx.x >> 2, ch = blockIdx.x & 3;
      if (tid < 128) {
        u2 hv;
        asm volatile("global_load_dwordx2 %0, %1, off sc0 sc1\n\ts_waitcnt vmcnt(0)"
                     : "=&v"(hv) : "v"((const void*)(hN + b * 512 + tid * 4)) : "memory");
        *(u2*)&sm.a.hs[tid * 4] = hv;
      }
      if (tid < 256) sm.a.rvacc[tid] = 0.f;
      f4 sdv = {1.f, 1.f, 1.f, 1.f};
      unsigned luv = 0;
      if (t > 0) {
        asm volatile(
            "global_load_dwordx4 %0, %2, off sc0 sc1\n\t"
            "global_load_dword %1, %3, off sc0 sc1\n\t"
            "s_waitcnt vmcnt(0)"
            : "=&v"(sdv), "=&v"(luv)
            : "v"((const void*)(sdW + b * 4)), "v"((const void*)(lu + b))
            : "memory");
      }
      __syncthreads();
      // keys (redundant per block) + out slice: 352 rows = 11 passes x 32
      for (int pp = 0; pp < 11; ++pp) {
        int idx = pp * 32 + wv * 4 + q;
        int wr; float bias;
        if (idx < 320) { wr = 128 + idx; bias = bkeyp[idx]; }
        else { wr = ch * 32 + (idx - 320); bias = boutp[wr]; }
        float acc = 0.f;
#pragma unroll
        for (int i = 0; i < 4; ++i) {
          bf8 w8 = *(const bf8*)&Wkb[(size_t)wr * 512 + i * 128 + s * 8];
          bf8 h8 = *(const bf8*)&sm.a.hs[i * 128 + s * 8];
#pragma unroll
          for (int j = 0; j < 8; ++j) acc += (float)w8[j] * (float)h8[j];
        }
        acc = red16(acc) + bias;
        if (s == 0) {
          if (idx < 256) sm.a.kbuf[idx] = acc;
          else if (idx < 320) sm.a.wkbuf[idx - 256] = acc;
          else out[((size_t)t * 64 + b) * 128 + wr] = acc;  // normal store
        }
      }
      __syncthreads();
      float4 kn[4];
#pragma unroll
      for (int r = 0; r < 4; ++r) {
        float4 k4 = *(float4*)&sm.a.kbuf[r * 64 + s * 4];
        float ss = k4.x * k4.x + k4.y * k4.y + k4.z * k4.z + k4.w * k4.w;
        ss = red16(ss);
        float iv = 1.f / (sqrtf(ss) + EPSF);
        kn[r].x = k4.x * iv; kn[r].y = k4.y * iv;
        kn[r].z = k4.z * iv; kn[r].w = k4.w * iv;
      }
      const float4 wk = *(float4*)&sm.a.wkbuf[s * 4];
      const float ip0 = 1.f / sdv.x, ip1 = 1.f / sdv.y;
      const float ip2 = 1.f / sdv.z, ip3 = 1.f / sdv.w;
      const float sa = sigf(alphap[0]);
      const int luB = (int)luv;
      float4* M4 = (float4*)M;
      float4 rva0 = {0,0,0,0}, rva1 = {0,0,0,0}, rva2 = {0,0,0,0}, rva3 = {0,0,0,0};
      float es0 = 0.f, es1 = 0.f, es2 = 0.f, es3 = 0.f;
      for (int i = 0; i < 16; ++i) {
        const int nl = wv * 64 + i * 4 + q;
        const int n = ch * 512 + nl;
        const size_t mi = ((size_t)b * 2048 + n) * 16 + s;
        float4 m4;
        if (t > 0) m4 = M4[mi];  // private, L2-resident
        else { m4.x = 1e-6f; m4.y = 1e-6f; m4.z = 1e-6f; m4.w = 1e-6f; }
        float4 ep;
        if (t > 0) ep = *(float4*)&rwPrev[nl * 4];  // own exps t-1, LDS
        else { ep.x = 0; ep.y = 0; ep.z = 0; ep.w = 0; }
        float ssm = m4.x * m4.x + m4.y * m4.y + m4.z * m4.z + m4.w * m4.w;
        float d0 = m4.x * kn[0].x + m4.y * kn[0].y + m4.z * kn[0].z + m4.w * kn[0].w;
        float d1 = m4.x * kn[1].x + m4.y * kn[1].y + m4.z * kn[1].z + m4.w * kn[1].w;
        float d2 = m4.x * kn[2].x + m4.y * kn[2].y + m4.z * kn[2].z + m4.w * kn[2].w;
        float d3 = m4.x * kn[3].x + m4.y * kn[3].y + m4.z * kn[3].z + m4.w * kn[3].w;
        ssm = red16(ssm);
        d0 = red16(d0); d1 = red16(d1); d2 = red16(d2); d3 = red16(d3);
        float iv = 1.f / (sqrtf(ssm) + EPSF);
        float e0 = __expf(d0 * iv), e1 = __expf(d1 * iv);
        float e2 = __expf(d2 * iv), e3 = __expf(d3 * iv);
        rva0.x += e0 * m4.x; rva0.y += e0 * m4.y; rva0.z += e0 * m4.z; rva0.w += e0 * m4.w;
        rva1.x += e1 * m4.x; rva1.y += e1 * m4.y; rva1.z += e1 * m4.z; rva1.w += e1 * m4.w;
        rva2.x += e2 * m4.x; rva2.y += e2 * m4.y; rva2.z += e2 * m4.z; rva2.w += e2 * m4.w;
        rva3.x += e3 * m4.x; rva3.y += e3 * m4.y; rva3.z += e3 * m4.z; rva3.w += e3 * m4.w;
        if (s == 0) {
          f4 ev = {e0, e1, e2, e3};
          *(f4*)&rwPrev[nl * 4] = ev;  // own reuse next step (LDS)
          st_coh16(rwCur + ((size_t)b * 2048 + n) * 4, ev);  // for finalize
          es0 += e0; es1 += e1; es2 += e2; es3 += e3;
        }
        float wps = ep.x * ip0 + ep.y * ip1 + ep.z * ip2 + ep.w * ip3;
        float onehot = (n == luB) ? 1.f : 0.f;
        float ww = sa * wps + (1.f - sa) * onehot;
        float keep = 1.f - onehot;
        float4 mn;
        mn.x = m4.x * keep + ww * wk.x;
        mn.y = m4.y * keep + ww * wk.y;
        mn.z = m4.z * keep + ww * wk.z;
        mn.w = m4.w * keep + ww * wk.w;
        M4[mi] = mn;  // private normal store
      }
      es0 += __shfl_xor(es0, 16); es0 += __shfl_xor(es0, 32);
      es1 += __shfl_xor(es1, 16); es1 += __shfl_xor(es1, 32);
      es2 += __shfl_xor(es2, 16); es2 += __shfl_xor(es2, 32);
      es3 += __shfl_xor(es3, 16); es3 += __shfl_xor(es3, 32);
      if (lane == 0) {
        sm.a.wsum[wv * 4 + 0] = es0; sm.a.wsum[wv * 4 + 1] = es1;
        sm.a.wsum[wv * 4 + 2] = es2; sm.a.wsum[wv * 4 + 3] = es3;
      }
#define REDQ(v) { v += __shfl_xor(v, 16); v += __shfl_xor(v, 32); }
      REDQ(rva0.x) REDQ(rva0.y) REDQ(rva0.z) REDQ(rva0.w)
      REDQ(rva1.x) REDQ(rva1.y) REDQ(rva1.z) REDQ(rva1.w)
      REDQ(rva2.x) REDQ(rva2.y) REDQ(rva2.z) REDQ(rva2.w)
      REDQ(rva3.x) REDQ(rva3.y) REDQ(rva3.z) REDQ(rva3.w)
#undef REDQ
      if (q == 0) {
        atomicAdd(&sm.a.rvacc[0 * 64 + s * 4 + 0], rva0.x);
        atomicAdd(&sm.a.rvacc[0 * 64 + s * 4 + 1], rva0.y);
        atomicAdd(&sm.a.rvacc[0 * 64 + s * 4 + 2], rva0.z);
        atomicAdd(&sm.a.rvacc[0 * 64 + s * 4 + 3], rva0.w);
        atomicAdd(&sm.a.rvacc[1 * 64 + s * 4 + 0], rva1.x);
        atomicAdd(&sm.a.rvacc[1 * 64 + s * 4 + 1], rva1.y);
        atomicAdd(&sm.a.rvacc[1 * 64 + s * 4 + 2], rva1.z);
        atomicAdd(&sm.a.rvacc[1 * 64 + s * 4 + 3], rva1.w);
        atomicAdd(&sm.a.rvacc[2 * 64 + s * 4 + 0], rva2.x);
        atomicAdd(&sm.a.rvacc[2 * 64 + s * 4 + 1], rva2.y);
        atomicAdd(&sm.a.rvacc[2 * 64 + s * 4 + 2], rva2.z);
        atomicAdd(&sm.a.rvacc[2 * 64 + s * 4 + 3], rva2.w);
        atomicAdd(&sm.a.rvacc[3 * 64 + s * 4 + 0], rva3.x);
        atomicAdd(&sm.a.rvacc[3 * 64 + s * 4 + 1], rva3.y);
        atomicAdd(&sm.a.rvacc[3 * 64 + s * 4 + 2], rva3.z);
        atomicAdd(&sm.a.rvacc[3 * 64 + s * 4 + 3], rva3.w);
      }
      __syncthreads();
      if (tid < 4) {
        float ssum = 0.f;
        for (int w8 = 0; w8 < 8; ++w8) ssum += sm.a.wsum[w8 * 4 + tid];
        st_coh4(dp + (b * 4 + tid) * 4 + ch, ssum);  // denom partial
      }
      if (tid < 256) {
        float v = sm.a.rvacc[tid];
        atomicAdd(rvW + b * 256 + tid, v);  // device-scope, at MALL
      }
    }
    gsync(bar, ++rnd);
  }
}

extern "C" void kernel_launch(void* const* d_in, const int* in_sizes, int n_in,
                              void* d_out, int out_size, void* d_ws, size_t ws_size,
                              hipStream_t stream) {
  const float* x_seq = (const float*)d_in[0];
  const float* Wih = (const float*)d_in[1];
  const float* Whh = (const float*)d_in[2];
  const float* bih = (const float*)d_in[3];
  const float* bhh = (const float*)d_in[4];
  const float* Wout = (const float*)d_in[5];
  const float* bout = (const float*)d_in[6];
  const float* Wkey = (const float*)d_in[7];
  const float* bkey = (const float*)d_in[8];
  const float* alpha = (const float*)d_in[9];
  const float* gamma = (const float*)d_in[10];
  float* out = (float*)d_out;
  char* ws = (char*)d_ws;

  // zero the barrier flag region (ws is re-poisoned before every call)
  hipMemsetAsync(ws + 38673408, 0, 20480, stream);
  mann_mega<<<256, 512, 0, stream>>>(x_seq, Wih, Whh, bih, bhh, Wout, bout,
                                     Wkey, bkey, alpha, gamma, out, ws);
}

// Round 7
// 5677.541 us; speedup vs baseline: 2.7222x; 1.5011x over previous
//
#include <hip/hip_runtime.h>
#include <hip/hip_bf16.h>

// IN=128, H=512, N=2048, W=64, OUT=128, R=4, T=128, B=64
// gate K=896 (x 0:128 | read_vec 128:384 | h 384:896), gate rows 2048
// Wkb rows: 0..127 = Wout, 128..447 = Wkey (read keys 128..383, write key 384..447)
//
// R7 core change: M (per-block 512x64 fp32 slice = 128 KB) lives in LDS for the
// whole kernel. R6 counters proved M round-trips to HBM every step (61 MB/step)
// because 32 blocks/XCD x 128 KB = 4 MB = the entire per-XCD L2 -> thrash.
// Coherence model unchanged: block-private normal-cached, cross-block via
// sc0 sc1 write-through stores + agent-relaxed atomic loads, no fences,
// s_waitcnt vmcnt(0) before each barrier arrival.
#define EPSF 1e-8f

typedef __attribute__((ext_vector_type(8))) __bf16 bf8;
typedef __attribute__((ext_vector_type(4))) float f4;
typedef unsigned long long ull;

__device__ __forceinline__ short f2bf(float f) {
  union { __hip_bfloat16 b; short s; } u;
  u.b = __float2bfloat16(f);
  return u.s;
}
__device__ __forceinline__ float sigf(float x) { return 1.f / (1.f + __expf(-x)); }
__device__ __forceinline__ float red16(float v) {
  v += __shfl_xor(v, 1); v += __shfl_xor(v, 2);
  v += __shfl_xor(v, 4); v += __shfl_xor(v, 8);
  return v;
}

// coherent (MALL-visible) helpers
__device__ __forceinline__ void st_coh16(void* p, f4 v) {
  asm volatile("global_store_dwordx4 %0, %1, off sc0 sc1" :: "v"(p), "v"(v) : "memory");
}
__device__ __forceinline__ void st_coh8u(void* p, ull v) {
  asm volatile("global_store_dwordx2 %0, %1, off sc0 sc1" :: "v"(p), "v"(v) : "memory");
}
__device__ __forceinline__ void st_coh4(void* p, float v) {
  asm volatile("global_store_dword %0, %1, off sc0 sc1" :: "v"(p), "v"(v) : "memory");
}
__device__ __forceinline__ void st_coh4u(void* p, unsigned v) {
  asm volatile("global_store_dword %0, %1, off sc0 sc1" :: "v"(p), "v"(v) : "memory");
}
__device__ __forceinline__ void st_coh2(void* p, unsigned v) {
  asm volatile("global_store_short %0, %1, off sc0 sc1" :: "v"(p), "v"(v) : "memory");
}
// agent-relaxed atomic load = sc0 sc1 load, compiler-scheduled waitcnt
__device__ __forceinline__ ull ald8(const void* p) {
  return __hip_atomic_load((const ull*)p, __ATOMIC_RELAXED, __HIP_MEMORY_SCOPE_AGENT);
}
__device__ __forceinline__ unsigned ald4(const void* p) {
  return __hip_atomic_load((const unsigned*)p, __ATOMIC_RELAXED, __HIP_MEMORY_SCOPE_AGENT);
}

#define LD8X4(v0,v1,v2,v3,v4,v5,v6,v7,p0,p1,p2,p3,p4,p5,p6,p7) \
  asm volatile( \
    "global_load_dwordx4 %0, %8, off sc0 sc1\n\t" \
    "global_load_dwordx4 %1, %9, off sc0 sc1\n\t" \
    "global_load_dwordx4 %2, %10, off sc0 sc1\n\t" \
    "global_load_dwordx4 %3, %11, off sc0 sc1\n\t" \
    "global_load_dwordx4 %4, %12, off sc0 sc1\n\t" \
    "global_load_dwordx4 %5, %13, off sc0 sc1\n\t" \
    "global_load_dwordx4 %6, %14, off sc0 sc1\n\t" \
    "global_load_dwordx4 %7, %15, off sc0 sc1\n\t" \
    "s_waitcnt vmcnt(0)" \
    : "=&v"(v0),"=&v"(v1),"=&v"(v2),"=&v"(v3),"=&v"(v4),"=&v"(v5),"=&v"(v6),"=&v"(v7) \
    : "v"(p0),"v"(p1),"v"(p2),"v"(p3),"v"(p4),"v"(p5),"v"(p6),"v"(p7) : "memory")

// Grid barrier (R6 design, proven): own-flag arrival, checker block 255,
// 8 release lines, relaxed loads, no fences.
__device__ __forceinline__ void gsync(unsigned* bar, unsigned k) {
  asm volatile("s_waitcnt vmcnt(0)" ::: "memory");
  __syncthreads();
  if (threadIdx.x == 0)
    __hip_atomic_store(&bar[blockIdx.x * 16], k, __ATOMIC_RELAXED,
                       __HIP_MEMORY_SCOPE_AGENT);
  if (blockIdx.x == 255) {
    if (threadIdx.x < 64) {
      const int l = threadIdx.x;
      for (;;) {
        unsigned mn = 0xffffffffu;
#pragma unroll
        for (int j = 0; j < 4; ++j) {
          unsigned v = __hip_atomic_load(&bar[(l * 4 + j) * 16], __ATOMIC_RELAXED,
                                         __HIP_MEMORY_SCOPE_AGENT);
          mn = v < mn ? v : mn;
        }
        if (__all(mn >= k)) break;
        __builtin_amdgcn_s_sleep(1);
      }
      if (l < 8)
        __hip_atomic_store(&bar[4096 + l * 16], k, __ATOMIC_RELAXED,
                           __HIP_MEMORY_SCOPE_AGENT);
    }
  } else if (threadIdx.x == 0) {
    const unsigned g = blockIdx.x >> 5;
    while (__hip_atomic_load(&bar[4096 + g * 16], __ATOMIC_RELAXED,
                             __HIP_MEMORY_SCOPE_AGENT) < k)
      __builtin_amdgcn_s_sleep(1);
  }
  __syncthreads();
}

struct StReg { ull a, b; };

__global__ __launch_bounds__(512, 2) void mann_mega(
    const float* __restrict__ x_seq, const float* __restrict__ Wih,
    const float* __restrict__ Whh, const float* __restrict__ bih,
    const float* __restrict__ bhh, const float* __restrict__ Wout,
    const float* __restrict__ boutp, const float* __restrict__ Wkey,
    const float* __restrict__ bkeyp, const float* __restrict__ alphap,
    const float* __restrict__ gammap, float* __restrict__ out, char* ws) {
  float* rwb0 = (float*)(ws + 33554432);       // 2097152  exps [b][n][r], sc1
  float* rwb1 = (float*)(ws + 35651584);       // 2097152
  float* usage = (float*)(ws + 37748736);      // 524288   private (finalize)
  float* cst = (float*)(ws + 38273024);        // 131072   private (gates)
  short* hb0 = (short*)(ws + 38404096);        // 65536    coherent
  short* hb1 = (short*)(ws + 38469632);        // 65536
  float* rv0 = (float*)(ws + 38535168);        // 65536    atomic-reduced rv
  float* rv1 = (float*)(ws + 38600704);        // 65536
  float* dp = (float*)(ws + 38666240);         // 4096     denom partials
  float* sd0 = (float*)(ws + 38670336);        // 1024     denoms [b][r]
  float* sd1 = (float*)(ws + 38671360);        // 1024
  unsigned* lu = (unsigned*)(ws + 38672384);   // 1024
  unsigned* bar = (unsigned*)(ws + 38673408);  // 20480 (host memset 0)
  short* Wc = (short*)(ws + 38693888);         // 3670016
  short* Wkb = (short*)(ws + 42363904);        // 458752 -> end 42822656

  // M slice for this block: [nl 0..511][w 0..63] fp32, resident all 128 steps
  __shared__ float Mlds[512 * 64];             // 131072 B
  __shared__ union {
    struct { short stage[4][2048]; } g;        // 16384 B; gbuf aliases post-loop
    struct { float sv[512]; int si[512]; } m;  // finalize argmin
    struct { short hs[512]; float kbuf[256]; float wkbuf[64];
             float rvacc[256]; float wsum[32]; float wps[512]; } a;  // PA
  } sm;
  __shared__ float denl[256];

  const int tid = threadIdx.x;
  const int lane = tid & 63;
  const int wv = tid >> 6;
  const int s = lane & 15;
  const int q = lane >> 4;
  unsigned rnd = 0;

  // ---------------- prologue: weight conversion + lu init ----------------
  {
    const unsigned gid = blockIdx.x * 512 + tid;
    const unsigned gs = 256 * 512;
    for (unsigned i4 = gid; i4 < 458752u; i4 += gs) {  // Wc: 2048x896 shorts
      unsigned e = i4 * 4;
      unsigned row = e / 896u, k = e - row * 896u;
      float4 v = (k < 384u) ? *(const float4*)&Wih[row * 384u + k]
                            : *(const float4*)&Whh[row * 512u + (k - 384u)];
      union { short4 s4; ull u; } o;
      o.s4.x = f2bf(v.x); o.s4.y = f2bf(v.y); o.s4.z = f2bf(v.z); o.s4.w = f2bf(v.w);
      st_coh8u(Wc + e, o.u);
    }
    for (unsigned i4 = gid; i4 < 57344u; i4 += gs) {  // Wkb: 448x512 shorts
      unsigned e = i4 * 4;
      unsigned row = e >> 9, k = e & 511u;
      float4 v = (row < 128u) ? *(const float4*)&Wout[row * 512u + k]
                              : *(const float4*)&Wkey[(row - 128u) * 512u + k];
      union { short4 s4; ull u; } o;
      o.s4.x = f2bf(v.x); o.s4.y = f2bf(v.y); o.s4.z = f2bf(v.z); o.s4.w = f2bf(v.w);
      st_coh8u(Wkb + e, o.u);
    }
    if (gid < 64u) st_coh4u(lu + gid, 0u);  // lu_0 = argmin(zeros) = 0
  }
  gsync(bar, ++rnd);

  for (int t = 0; t < 128; ++t) {
    const int p = t & 1;
    short* hN = p ? hb1 : hb0;
    const short* hP = p ? hb0 : hb1;
    float* rwCur = p ? rwb1 : rwb0;       // exps of step t (sc1 in PA)
    const float* rwM1 = p ? rwb0 : rwb1;  // exps of step t-1
    const float* rwM2 = rwCur;            // exps of step t-2 (stale buffer)
    float* sdW = p ? sd1 : sd0;           // denom_{t-1}, written by finalize_t
    const float* sdM2 = p ? sd0 : sd1;    // denom_{t-2}
    float* rvW = p ? rv1 : rv0;           // atomic target of PA_t
    const float* rvR = p ? rv0 : rv1;     // reduced rv of step t-1

    // ========== P1 phase ==========
    if (blockIdx.x < 64) {
      // ---- gates GEMM (chunk-32, 4-deep pipelined staging) + LSTM cell ----
      const int j0 = blockIdx.x * 8;
      if (tid < 256) {
        float iv = 1.f;
        if (t > 0) {
          union { ull u; float2 f; } a, b2;
          a.u = ald8(dp + tid * 4); b2.u = ald8(dp + tid * 4 + 2);
          iv = 1.f / (a.f.x + a.f.y + b2.f.x + b2.f.y);
        }
        denl[tid] = iv;  // 1/denom_{t-1}[b*4+r]
      }
      const int row = lane;       // batch row this thread stages
      const int k4 = wv;          // 0..7, covers k_local = k4*4
      // chunk c: k0=c*32; c<4: x_seq | 4<=c<12: read_vec | c>=12: h
      auto stage_load = [&](int c) -> StReg {
        StReg r; r.a = 0; r.b = 0;
        if (c < 4) {
          float4 v = *(const float4*)&x_seq[((size_t)t * 64 + row) * 128 + c * 32 + k4 * 4];
          union { float2 f; ull u; } u0, u1;
          u0.f.x = v.x; u0.f.y = v.y; u1.f.x = v.z; u1.f.y = v.w;
          r.a = u0.u; r.b = u1.u;
        } else if (c < 12) {
          if (t > 0) {
            int col = (c - 4) * 32 + k4 * 4;
            r.a = ald8(rvR + row * 256 + col);
            r.b = ald8(rvR + row * 256 + col + 2);
          }
        } else {
          if (t > 0) r.a = ald8(hP + row * 512 + (c - 12) * 32 + k4 * 4);
        }
        return r;
      };
      auto stage_store = [&](short* buf, int c, StReg r) {
        short4 o;
        if (c < 4) {
          union { ull u; float2 f; } a, b2; a.u = r.a; b2.u = r.b;
          o.x = f2bf(a.f.x); o.y = f2bf(a.f.y); o.z = f2bf(b2.f.x); o.w = f2bf(b2.f.y);
        } else if (c < 12) {
          union { ull u; float2 f; } a, b2; a.u = r.a; b2.u = r.b;
          int col = (c - 4) * 32 + k4 * 4;
          float iv = denl[row * 4 + (col >> 6)];
          o.x = f2bf(a.f.x * iv); o.y = f2bf(a.f.y * iv);
          o.z = f2bf(b2.f.x * iv); o.w = f2bf(b2.f.y * iv);
        } else {
          union { ull u; short4 s4; } a; a.u = r.a; o = a.s4;
        }
        int idx = (row >> 4) * 512 + ((row & 15) + 16 * ((k4 >> 1) & 3)) * 8 + (k4 & 1) * 4;
        *(short4*)&buf[idx] = o;
      };
      __syncthreads();  // denl visible before rv stores use it
      {
        StReg r0 = stage_load(0), r1 = stage_load(1), r2 = stage_load(2);
        stage_store(sm.g.stage[0], 0, r0);
        stage_store(sm.g.stage[1], 1, r1);
        stage_store(sm.g.stage[2], 2, r2);
        StReg ra = stage_load(3);
        StReg rb = stage_load(4);
        __syncthreads();
        const int msl = wv >> 1, nh = wv & 1;
        const int rr = nh * 16 + s;
        const int gg = rr >> 3, jj = rr & 7;
        const size_t wrow = (size_t)(gg * 512 + j0 + jj) * 896;
        f4 acc = {0.f, 0.f, 0.f, 0.f};
        for (int c = 0; c < 28; ++c) {
          StReg rn;
          if (c + 5 < 28) rn = stage_load(c + 5);
          bf8 a = *(const bf8*)&sm.g.stage[c & 3][msl * 512 + lane * 8];
          bf8 bb = *(const bf8*)&Wc[wrow + c * 32 + q * 8];
          acc = __builtin_amdgcn_mfma_f32_16x16x32_bf16(a, bb, acc, 0, 0, 0);
          if (c + 3 < 28) { stage_store(sm.g.stage[(c + 3) & 3], c + 3, ra); ra = rb; rb = rn; }
          __syncthreads();
        }
        float* gbuf = (float*)sm.g.stage;  // aliases stage bufs (reads done)
#pragma unroll
        for (int reg = 0; reg < 4; ++reg) {
          int bat = msl * 16 + q * 4 + reg;
          gbuf[bat * 33 + rr] = acc[reg];
        }
      }
      __syncthreads();
      {
        const float* gbuf = (const float*)sm.g.stage;
        int b = tid >> 3, jj = tid & 7, j = j0 + jj;
        float gi = gbuf[b * 33 + jj] + bih[j] + bhh[j];
        float gf = gbuf[b * 33 + 8 + jj] + bih[512 + j] + bhh[512 + j];
        float gg2 = gbuf[b * 33 + 16 + jj] + bih[1024 + j] + bhh[1024 + j];
        float go = gbuf[b * 33 + 24 + jj] + bih[1536 + j] + bhh[1536 + j];
        float co = (t == 0) ? 0.f : cst[b * 512 + j];  // private cached
        float cn = sigf(gf) * co + sigf(gi) * tanhf(gg2);
        float hn = sigf(go) * tanhf(cn);
        cst[b * 512 + j] = cn;
        union { __hip_bfloat16 b16; unsigned short us; } hu;
        hu.b16 = __float2bfloat16(hn);
        st_coh2(hN + b * 512 + j, (unsigned)hu.us);
      }
    } else if (blockIdx.x < 128) {
      // ---- finalize step t-1: denoms -> sdW, usage update, argmin -> lu ----
      if (t > 0) {
        const int b = blockIdx.x - 64;
        f4 dp0, dp1, dp2, dp3, sm2;
        unsigned luv;
        asm volatile(
            "global_load_dwordx4 %0, %6, off sc0 sc1\n\t"
            "global_load_dwordx4 %1, %7, off sc0 sc1\n\t"
            "global_load_dwordx4 %2, %8, off sc0 sc1\n\t"
            "global_load_dwordx4 %3, %9, off sc0 sc1\n\t"
            "global_load_dwordx4 %4, %10, off sc0 sc1\n\t"
            "global_load_dword %5, %11, off sc0 sc1\n\t"
            "s_waitcnt vmcnt(0)"
            : "=&v"(dp0), "=&v"(dp1), "=&v"(dp2), "=&v"(dp3), "=&v"(sm2), "=&v"(luv)
            : "v"((const void*)(dp + (b * 4 + 0) * 4)),
              "v"((const void*)(dp + (b * 4 + 1) * 4)),
              "v"((const void*)(dp + (b * 4 + 2) * 4)),
              "v"((const void*)(dp + (b * 4 + 3) * 4)),
              "v"((const void*)(sdM2 + b * 4)), "v"((const void*)(lu + b))
            : "memory");
        float d0 = dp0.x + dp0.y + dp0.z + dp0.w;
        float d1 = dp1.x + dp1.y + dp1.z + dp1.w;
        float d2 = dp2.x + dp2.y + dp2.z + dp2.w;
        float d3 = dp3.x + dp3.y + dp3.z + dp3.w;
        if (tid == 0) { f4 dv = {d0, d1, d2, d3}; st_coh16(sdW + b * 4, dv); }
        float iC0 = 1.f / d0, iC1 = 1.f / d1, iC2 = 1.f / d2, iC3 = 1.f / d3;
        float iO0 = 0, iO1 = 0, iO2 = 0, iO3 = 0;
        if (t > 1) { iO0 = 1.f / sm2.x; iO1 = 1.f / sm2.y; iO2 = 1.f / sm2.z; iO3 = 1.f / sm2.w; }
        const float sa = sigf(alphap[0]);
        const float ga = gammap[0];
        const int luB = (int)luv;
        f4 ec[4], eo[4];
        {
          const void* pc[4]; const void* po[4];
#pragma unroll
          for (int i = 0; i < 4; ++i) {
            int n = i * 512 + tid;
            pc[i] = (const void*)(rwM1 + ((size_t)b * 2048 + n) * 4);
            po[i] = (const void*)(rwM2 + ((size_t)b * 2048 + n) * 4);
          }
          LD8X4(ec[0], ec[1], ec[2], ec[3], eo[0], eo[1], eo[2], eo[3],
                pc[0], pc[1], pc[2], pc[3], po[0], po[1], po[2], po[3]);
        }
        float vm = INFINITY;
        int im = 0x7fffffff;
#pragma unroll
        for (int i = 0; i < 4; ++i) {
          int n = i * 512 + tid;
          float wps = (t > 1) ? (eo[i].x * iO0 + eo[i].y * iO1 + eo[i].z * iO2 + eo[i].w * iO3)
                              : 0.f;
          float ww = sa * wps + (1.f - sa) * ((n == luB) ? 1.f : 0.f);
          float sn = ec[i].x * iC0 + ec[i].y * iC1 + ec[i].z * iC2 + ec[i].w * iC3;
          float uo = (t == 1) ? 0.f : usage[b * 2048 + n];  // private cached
          float u = ga * uo + sn + ww;
          usage[b * 2048 + n] = u;
          if (u < vm) { vm = u; im = n; }  // n strictly increasing per thread
        }
        sm.m.sv[tid] = vm; sm.m.si[tid] = im;
        __syncthreads();
        for (int off = 256; off > 0; off >>= 1) {
          if (tid < off) {
            float v2 = sm.m.sv[tid + off]; int j2 = sm.m.si[tid + off];
            if (v2 < sm.m.sv[tid] || (v2 == sm.m.sv[tid] && j2 < sm.m.si[tid])) {
              sm.m.sv[tid] = v2; sm.m.si[tid] = j2;
            }
          }
          __syncthreads();
        }
        if (tid == 0) st_coh4u(lu + b, (unsigned)sm.m.si[0]);
      }
    } else if (blockIdx.x < 192) {
      // ---- zero rvW for PA_t's atomics ----
      const int bz = blockIdx.x - 128;
      if (tid < 64) { f4 z = {0, 0, 0, 0}; st_coh16(rvW + bz * 256 + tid * 4, z); }
    }
    gsync(bar, ++rnd);

    // ========== PA phase: keys/out + fused M-pass (M in LDS) ==========
    {
      const int b = blockIdx.x >> 2, ch = blockIdx.x & 3;
      if (tid < 128) {
        union { ull u; uint2 v; } hv;
        hv.u = ald8(hN + b * 512 + tid * 4);
        *(uint2*)&sm.a.hs[tid * 4] = hv.v;
      }
      if (tid < 256) sm.a.rvacc[tid] = 0.f;
      unsigned luv = 0;
      if (t > 0) {
        luv = ald4(lu + b);
        // precompute w_prev sums: wps[nl] = sum_r exp_{t-1}[r]/denom_{t-1}[r]
        union { ull u; float2 f; } s0, s1, e0, e1;
        s0.u = ald8(sdW + b * 4); s1.u = ald8(sdW + b * 4 + 2);
        const size_t eb = ((size_t)b * 2048 + ch * 512 + tid) * 4;
        e0.u = ald8(rwM1 + eb); e1.u = ald8(rwM1 + eb + 2);
        sm.a.wps[tid] = e0.f.x / s0.f.x + e0.f.y / s0.f.y +
                        e1.f.x / s1.f.x + e1.f.y / s1.f.y;
      } else {
        sm.a.wps[tid] = 0.f;
      }
      __syncthreads();
      // keys (redundant per block) + out slice: 352 rows = 11 passes x 32
      for (int pp = 0; pp < 11; ++pp) {
        int idx = pp * 32 + wv * 4 + q;
        int wr; float bias;
        if (idx < 320) { wr = 128 + idx; bias = bkeyp[idx]; }
        else { wr = ch * 32 + (idx - 320); bias = boutp[wr]; }
        float acc = 0.f;
#pragma unroll
        for (int i = 0; i < 4; ++i) {
          bf8 w8 = *(const bf8*)&Wkb[(size_t)wr * 512 + i * 128 + s * 8];
          bf8 h8 = *(const bf8*)&sm.a.hs[i * 128 + s * 8];
#pragma unroll
          for (int j = 0; j < 8; ++j) acc += (float)w8[j] * (float)h8[j];
        }
        acc = red16(acc) + bias;
        if (s == 0) {
          if (idx < 256) sm.a.kbuf[idx] = acc;
          else if (idx < 320) sm.a.wkbuf[idx - 256] = acc;
          else out[((size_t)t * 64 + b) * 128 + wr] = acc;  // normal store
        }
      }
      __syncthreads();
      float4 kn[4];
#pragma unroll
      for (int r = 0; r < 4; ++r) {
        float4 k4 = *(float4*)&sm.a.kbuf[r * 64 + s * 4];
        float ss = k4.x * k4.x + k4.y * k4.y + k4.z * k4.z + k4.w * k4.w;
        ss = red16(ss);
        float iv = 1.f / (sqrtf(ss) + EPSF);
        kn[r].x = k4.x * iv; kn[r].y = k4.y * iv;
        kn[r].z = k4.z * iv; kn[r].w = k4.w * iv;
      }
      const float4 wk = *(float4*)&sm.a.wkbuf[s * 4];
      const float sa = sigf(alphap[0]);
      const int luB = (int)luv;
      float4 rva0 = {0,0,0,0}, rva1 = {0,0,0,0}, rva2 = {0,0,0,0}, rva3 = {0,0,0,0};
      float es0 = 0.f, es1 = 0.f, es2 = 0.f, es3 = 0.f;
      for (int i = 0; i < 16; ++i) {
        const int nl = wv * 64 + i * 4 + q;
        const int n = ch * 512 + nl;
        float4 m4;
        if (t > 0) m4 = *(float4*)&Mlds[nl * 64 + s * 4];
        else { m4.x = 1e-6f; m4.y = 1e-6f; m4.z = 1e-6f; m4.w = 1e-6f; }
        float ssm = m4.x * m4.x + m4.y * m4.y + m4.z * m4.z + m4.w * m4.w;
        float d0 = m4.x * kn[0].x + m4.y * kn[0].y + m4.z * kn[0].z + m4.w * kn[0].w;
        float d1 = m4.x * kn[1].x + m4.y * kn[1].y + m4.z * kn[1].z + m4.w * kn[1].w;
        float d2 = m4.x * kn[2].x + m4.y * kn[2].y + m4.z * kn[2].z + m4.w * kn[2].w;
        float d3 = m4.x * kn[3].x + m4.y * kn[3].y + m4.z * kn[3].z + m4.w * kn[3].w;
        ssm = red16(ssm);
        d0 = red16(d0); d1 = red16(d1); d2 = red16(d2); d3 = red16(d3);
        float iv = 1.f / (sqrtf(ssm) + EPSF);
        float e0 = __expf(d0 * iv), e1 = __expf(d1 * iv);
        float e2 = __expf(d2 * iv), e3 = __expf(d3 * iv);
        rva0.x += e0 * m4.x; rva0.y += e0 * m4.y; rva0.z += e0 * m4.z; rva0.w += e0 * m4.w;
        rva1.x += e1 * m4.x; rva1.y += e1 * m4.y; rva1.z += e1 * m4.z; rva1.w += e1 * m4.w;
        rva2.x += e2 * m4.x; rva2.y += e2 * m4.y; rva2.z += e2 * m4.z; rva2.w += e2 * m4.w;
        rva3.x += e3 * m4.x; rva3.y += e3 * m4.y; rva3.z += e3 * m4.z; rva3.w += e3 * m4.w;
        if (s == 0) {
          f4 ev = {e0, e1, e2, e3};
          st_coh16(rwCur + ((size_t)b * 2048 + n) * 4, ev);  // for finalize/wps
          es0 += e0; es1 += e1; es2 += e2; es3 += e3;
        }
        float wps = sm.a.wps[nl];
        float onehot = (n == luB) ? 1.f : 0.f;
        float ww = sa * wps + (1.f - sa) * onehot;
        float keep = 1.f - onehot;
        float4 mn;
        mn.x = m4.x * keep + ww * wk.x;
        mn.y = m4.y * keep + ww * wk.y;
        mn.z = m4.z * keep + ww * wk.z;
        mn.w = m4.w * keep + ww * wk.w;
        *(float4*)&Mlds[nl * 64 + s * 4] = mn;  // LDS-resident M
      }
      es0 += __shfl_xor(es0, 16); es0 += __shfl_xor(es0, 32);
      es1 += __shfl_xor(es1, 16); es1 += __shfl_xor(es1, 32);
      es2 += __shfl_xor(es2, 16); es2 += __shfl_xor(es2, 32);
      es3 += __shfl_xor(es3, 16); es3 += __shfl_xor(es3, 32);
      if (lane == 0) {
        sm.a.wsum[wv * 4 + 0] = es0; sm.a.wsum[wv * 4 + 1] = es1;
        sm.a.wsum[wv * 4 + 2] = es2; sm.a.wsum[wv * 4 + 3] = es3;
      }
#define REDQ(v) { v += __shfl_xor(v, 16); v += __shfl_xor(v, 32); }
      REDQ(rva0.x) REDQ(rva0.y) REDQ(rva0.z) REDQ(rva0.w)
      REDQ(rva1.x) REDQ(rva1.y) REDQ(rva1.z) REDQ(rva1.w)
      REDQ(rva2.x) REDQ(rva2.y) REDQ(rva2.z) REDQ(rva2.w)
      REDQ(rva3.x) REDQ(rva3.y) REDQ(rva3.z) REDQ(rva3.w)
#undef REDQ
      if (q == 0) {
        atomicAdd(&sm.a.rvacc[0 * 64 + s * 4 + 0], rva0.x);
        atomicAdd(&sm.a.rvacc[0 * 64 + s * 4 + 1], rva0.y);
        atomicAdd(&sm.a.rvacc[0 * 64 + s * 4 + 2], rva0.z);
        atomicAdd(&sm.a.rvacc[0 * 64 + s * 4 + 3], rva0.w);
        atomicAdd(&sm.a.rvacc[1 * 64 + s * 4 + 0], rva1.x);
        atomicAdd(&sm.a.rvacc[1 * 64 + s * 4 + 1], rva1.y);
        atomicAdd(&sm.a.rvacc[1 * 64 + s * 4 + 2], rva1.z);
        atomicAdd(&sm.a.rvacc[1 * 64 + s * 4 + 3], rva1.w);
        atomicAdd(&sm.a.rvacc[2 * 64 + s * 4 + 0], rva2.x);
        atomicAdd(&sm.a.rvacc[2 * 64 + s * 4 + 1], rva2.y);
        atomicAdd(&sm.a.rvacc[2 * 64 + s * 4 + 2], rva2.z);
        atomicAdd(&sm.a.rvacc[2 * 64 + s * 4 + 3], rva2.w);
        atomicAdd(&sm.a.rvacc[3 * 64 + s * 4 + 0], rva3.x);
        atomicAdd(&sm.a.rvacc[3 * 64 + s * 4 + 1], rva3.y);
        atomicAdd(&sm.a.rvacc[3 * 64 + s * 4 + 2], rva3.z);
        atomicAdd(&sm.a.rvacc[3 * 64 + s * 4 + 3], rva3.w);
      }
      __syncthreads();
      if (tid < 4) {
        float ssum = 0.f;
        for (int w8 = 0; w8 < 8; ++w8) ssum += sm.a.wsum[w8 * 4 + tid];
        st_coh4(dp + (b * 4 + tid) * 4 + ch, ssum);  // denom partial
      }
      if (tid < 256) {
        float v = sm.a.rvacc[tid];
        atomicAdd(rvW + b * 256 + tid, v);  // device-scope, at MALL
      }
    }
    gsync(bar, ++rnd);
  }
}

extern "C" void kernel_launch(void* const* d_in, const int* in_sizes, int n_in,
                              void* d_out, int out_size, void* d_ws, size_t ws_size,
                              hipStream_t stream) {
  const float* x_seq = (const float*)d_in[0];
  const float* Wih = (const float*)d_in[1];
  const float* Whh = (const float*)d_in[2];
  const float* bih = (const float*)d_in[3];
  const float* bhh = (const float*)d_in[4];
  const float* Wout = (const float*)d_in[5];
  const float* bout = (const float*)d_in[6];
  const float* Wkey = (const float*)d_in[7];
  const float* bkey = (const float*)d_in[8];
  const float* alpha = (const float*)d_in[9];
  const float* gamma = (const float*)d_in[10];
  float* out = (float*)d_out;
  char* ws = (char*)d_ws;

  // zero the barrier flag region (ws is re-poisoned before every call)
  hipMemsetAsync(ws + 38673408, 0, 20480, stream);
  mann_mega<<<256, 512, 0, stream>>>(x_seq, Wih, Whh, bih, bhh, Wout, bout,
                                     Wkey, bkey, alpha, gamma, out, ws);
}

// Round 8
// 5650.459 us; speedup vs baseline: 2.7353x; 1.0048x over previous
//
#include <hip/hip_runtime.h>
#include <hip/hip_bf16.h>

// IN=128, H=512, N=2048, W=64, OUT=128, R=4, T=128, B=64
// gate K=896 (x 0:128 | read_vec 128:384 | h 384:896), gate rows 2048
// Wkb rows: 0..127 = Wout, 128..447 = Wkey (read keys 128..383, write key 384..447)
//
// R8: R7 (M in LDS, fence-free coherence) + two stall fixes:
//  (a) gates staging loads hoisted to registers before the MFMA loop
//  (b) LBAR (s_waitcnt lgkmcnt(0) + s_barrier) instead of __syncthreads in hot
//      loops -> no vmcnt(0) drain -> global loads pipeline across iterations.
#define EPSF 1e-8f

typedef __attribute__((ext_vector_type(8))) __bf16 bf8;
typedef __attribute__((ext_vector_type(4))) float f4;
typedef unsigned long long ull;

#define LBAR() do { asm volatile("s_waitcnt lgkmcnt(0)" ::: "memory"); \
                    __builtin_amdgcn_s_barrier(); } while (0)

__device__ __forceinline__ short f2bf(float f) {
  union { __hip_bfloat16 b; short s; } u;
  u.b = __float2bfloat16(f);
  return u.s;
}
__device__ __forceinline__ float sigf(float x) { return 1.f / (1.f + __expf(-x)); }
__device__ __forceinline__ float red16(float v) {
  v += __shfl_xor(v, 1); v += __shfl_xor(v, 2);
  v += __shfl_xor(v, 4); v += __shfl_xor(v, 8);
  return v;
}

// coherent (MALL-visible) helpers
__device__ __forceinline__ void st_coh16(void* p, f4 v) {
  asm volatile("global_store_dwordx4 %0, %1, off sc0 sc1" :: "v"(p), "v"(v) : "memory");
}
__device__ __forceinline__ void st_coh8u(void* p, ull v) {
  asm volatile("global_store_dwordx2 %0, %1, off sc0 sc1" :: "v"(p), "v"(v) : "memory");
}
__device__ __forceinline__ void st_coh4(void* p, float v) {
  asm volatile("global_store_dword %0, %1, off sc0 sc1" :: "v"(p), "v"(v) : "memory");
}
__device__ __forceinline__ void st_coh4u(void* p, unsigned v) {
  asm volatile("global_store_dword %0, %1, off sc0 sc1" :: "v"(p), "v"(v) : "memory");
}
__device__ __forceinline__ void st_coh2(void* p, unsigned v) {
  asm volatile("global_store_short %0, %1, off sc0 sc1" :: "v"(p), "v"(v) : "memory");
}
__device__ __forceinline__ ull ald8(const void* p) {
  return __hip_atomic_load((const ull*)p, __ATOMIC_RELAXED, __HIP_MEMORY_SCOPE_AGENT);
}
__device__ __forceinline__ unsigned ald4(const void* p) {
  return __hip_atomic_load((const unsigned*)p, __ATOMIC_RELAXED, __HIP_MEMORY_SCOPE_AGENT);
}

#define LD8X4(v0,v1,v2,v3,v4,v5,v6,v7,p0,p1,p2,p3,p4,p5,p6,p7) \
  asm volatile( \
    "global_load_dwordx4 %0, %8, off sc0 sc1\n\t" \
    "global_load_dwordx4 %1, %9, off sc0 sc1\n\t" \
    "global_load_dwordx4 %2, %10, off sc0 sc1\n\t" \
    "global_load_dwordx4 %3, %11, off sc0 sc1\n\t" \
    "global_load_dwordx4 %4, %12, off sc0 sc1\n\t" \
    "global_load_dwordx4 %5, %13, off sc0 sc1\n\t" \
    "global_load_dwordx4 %6, %14, off sc0 sc1\n\t" \
    "global_load_dwordx4 %7, %15, off sc0 sc1\n\t" \
    "s_waitcnt vmcnt(0)" \
    : "=&v"(v0),"=&v"(v1),"=&v"(v2),"=&v"(v3),"=&v"(v4),"=&v"(v5),"=&v"(v6),"=&v"(v7) \
    : "v"(p0),"v"(p1),"v"(p2),"v"(p3),"v"(p4),"v"(p5),"v"(p6),"v"(p7) : "memory")

// Grid barrier (R6/R7 proven design): own-flag arrival, checker block 255,
// 8 release lines, relaxed loads, no fences.
__device__ __forceinline__ void gsync(unsigned* bar, unsigned k) {
  asm volatile("s_waitcnt vmcnt(0)" ::: "memory");
  __syncthreads();
  if (threadIdx.x == 0)
    __hip_atomic_store(&bar[blockIdx.x * 16], k, __ATOMIC_RELAXED,
                       __HIP_MEMORY_SCOPE_AGENT);
  if (blockIdx.x == 255) {
    if (threadIdx.x < 64) {
      const int l = threadIdx.x;
      for (;;) {
        unsigned mn = 0xffffffffu;
#pragma unroll
        for (int j = 0; j < 4; ++j) {
          unsigned v = __hip_atomic_load(&bar[(l * 4 + j) * 16], __ATOMIC_RELAXED,
                                         __HIP_MEMORY_SCOPE_AGENT);
          mn = v < mn ? v : mn;
        }
        if (__all(mn >= k)) break;
        __builtin_amdgcn_s_sleep(1);
      }
      if (l < 8)
        __hip_atomic_store(&bar[4096 + l * 16], k, __ATOMIC_RELAXED,
                           __HIP_MEMORY_SCOPE_AGENT);
    }
  } else if (threadIdx.x == 0) {
    const unsigned g = blockIdx.x >> 5;
    while (__hip_atomic_load(&bar[4096 + g * 16], __ATOMIC_RELAXED,
                             __HIP_MEMORY_SCOPE_AGENT) < k)
      __builtin_amdgcn_s_sleep(1);
  }
  __syncthreads();
}

struct StReg { ull a, b; };

__global__ __launch_bounds__(512, 2) void mann_mega(
    const float* __restrict__ x_seq, const float* __restrict__ Wih,
    const float* __restrict__ Whh, const float* __restrict__ bih,
    const float* __restrict__ bhh, const float* __restrict__ Wout,
    const float* __restrict__ boutp, const float* __restrict__ Wkey,
    const float* __restrict__ bkeyp, const float* __restrict__ alphap,
    const float* __restrict__ gammap, float* __restrict__ out, char* ws) {
  float* rwb0 = (float*)(ws + 33554432);       // 2097152  exps [b][n][r], coherent
  float* rwb1 = (float*)(ws + 35651584);       // 2097152
  float* usage = (float*)(ws + 37748736);      // 524288   private (finalize)
  float* cst = (float*)(ws + 38273024);        // 131072   private (gates)
  short* hb0 = (short*)(ws + 38404096);        // 65536    coherent
  short* hb1 = (short*)(ws + 38469632);        // 65536
  float* rv0 = (float*)(ws + 38535168);        // 65536    atomic-reduced rv
  float* rv1 = (float*)(ws + 38600704);        // 65536
  float* dp = (float*)(ws + 38666240);         // 4096     denom partials
  float* sd0 = (float*)(ws + 38670336);        // 1024     denoms [b][r]
  float* sd1 = (float*)(ws + 38671360);        // 1024
  unsigned* lu = (unsigned*)(ws + 38672384);   // 1024
  unsigned* bar = (unsigned*)(ws + 38673408);  // 20480 (host memset 0)
  short* Wc = (short*)(ws + 38693888);         // 3670016
  short* Wkb = (short*)(ws + 42363904);        // 458752 -> end 42822656

  // M slice for this block: [nl 0..511][w 0..63] fp32, resident all 128 steps
  __shared__ float Mlds[512 * 64];             // 131072 B
  __shared__ union {
    struct { short stage[4][2048]; } g;        // 16384 B; gbuf aliases post-loop
    struct { float sv[512]; int si[512]; } m;  // finalize argmin
    struct { short hs[512]; float kbuf[256]; float wkbuf[64];
             float rvacc[256]; float wsum[32]; float wps[512]; } a;  // PA
  } sm;
  __shared__ float denl[256];

  const int tid = threadIdx.x;
  const int lane = tid & 63;
  const int wv = tid >> 6;
  const int s = lane & 15;
  const int q = lane >> 4;
  unsigned rnd = 0;

  // ---------------- prologue: weight conversion + lu init ----------------
  {
    const unsigned gid = blockIdx.x * 512 + tid;
    const unsigned gs = 256 * 512;
    for (unsigned i4 = gid; i4 < 458752u; i4 += gs) {  // Wc: 2048x896 shorts
      unsigned e = i4 * 4;
      unsigned row = e / 896u, k = e - row * 896u;
      float4 v = (k < 384u) ? *(const float4*)&Wih[row * 384u + k]
                            : *(const float4*)&Whh[row * 512u + (k - 384u)];
      union { short4 s4; ull u; } o;
      o.s4.x = f2bf(v.x); o.s4.y = f2bf(v.y); o.s4.z = f2bf(v.z); o.s4.w = f2bf(v.w);
      st_coh8u(Wc + e, o.u);
    }
    for (unsigned i4 = gid; i4 < 57344u; i4 += gs) {  // Wkb: 448x512 shorts
      unsigned e = i4 * 4;
      unsigned row = e >> 9, k = e & 511u;
      float4 v = (row < 128u) ? *(const float4*)&Wout[row * 512u + k]
                              : *(const float4*)&Wkey[(row - 128u) * 512u + k];
      union { short4 s4; ull u; } o;
      o.s4.x = f2bf(v.x); o.s4.y = f2bf(v.y); o.s4.z = f2bf(v.z); o.s4.w = f2bf(v.w);
      st_coh8u(Wkb + e, o.u);
    }
    if (gid < 64u) st_coh4u(lu + gid, 0u);  // lu_0 = argmin(zeros) = 0
  }
  gsync(bar, ++rnd);

  for (int t = 0; t < 128; ++t) {
    const int p = t & 1;
    short* hN = p ? hb1 : hb0;
    const short* hP = p ? hb0 : hb1;
    float* rwCur = p ? rwb1 : rwb0;       // exps of step t (coherent in PA)
    const float* rwM1 = p ? rwb0 : rwb1;  // exps of step t-1
    const float* rwM2 = rwCur;            // exps of step t-2 (stale buffer)
    float* sdW = p ? sd1 : sd0;           // denom_{t-1}, written by finalize_t
    const float* sdM2 = p ? sd0 : sd1;    // denom_{t-2}
    float* rvW = p ? rv1 : rv0;           // atomic target of PA_t
    const float* rvR = p ? rv0 : rv1;     // reduced rv of step t-1

    // ========== P1 phase ==========
    if (blockIdx.x < 64) {
      // ---- gates GEMM + LSTM cell; all staged loads hoisted to registers ----
      const int j0 = blockIdx.x * 8;
      if (tid < 256) {
        float iv = 1.f;
        if (t > 0) {
          union { ull u; float2 f; } a, b2;
          a.u = ald8(dp + tid * 4); b2.u = ald8(dp + tid * 4 + 2);
          iv = 1.f / (a.f.x + a.f.y + b2.f.x + b2.f.y);
        }
        denl[tid] = iv;  // 1/denom_{t-1}[b*4+r]
      }
      const int row = lane;       // batch row this thread stages
      const int k4 = wv;          // 0..7, covers k_local = k4*4
      // chunk c: k0=c*32; c<4: x_seq | 4<=c<12: read_vec | c>=12: h
      auto stage_load = [&](int c) -> StReg {
        StReg r; r.a = 0; r.b = 0;
        if (c < 4) {
          float4 v = *(const float4*)&x_seq[((size_t)t * 64 + row) * 128 + c * 32 + k4 * 4];
          union { float2 f; ull u; } u0, u1;
          u0.f.x = v.x; u0.f.y = v.y; u1.f.x = v.z; u1.f.y = v.w;
          r.a = u0.u; r.b = u1.u;
        } else if (c < 12) {
          if (t > 0) {
            int col = (c - 4) * 32 + k4 * 4;
            r.a = ald8(rvR + row * 256 + col);
            r.b = ald8(rvR + row * 256 + col + 2);
          }
        } else {
          if (t > 0) r.a = ald8(hP + row * 512 + (c - 12) * 32 + k4 * 4);
        }
        return r;
      };
      auto stage_store = [&](short* buf, int c, StReg r) {
        short4 o;
        if (c < 4) {
          union { ull u; float2 f; } a, b2; a.u = r.a; b2.u = r.b;
          o.x = f2bf(a.f.x); o.y = f2bf(a.f.y); o.z = f2bf(b2.f.x); o.w = f2bf(b2.f.y);
        } else if (c < 12) {
          union { ull u; float2 f; } a, b2; a.u = r.a; b2.u = r.b;
          int col = (c - 4) * 32 + k4 * 4;
          float iv = denl[row * 4 + (col >> 6)];
          o.x = f2bf(a.f.x * iv); o.y = f2bf(a.f.y * iv);
          o.z = f2bf(b2.f.x * iv); o.w = f2bf(b2.f.y * iv);
        } else {
          union { ull u; short4 s4; } a; a.u = r.a; o = a.s4;
        }
        int idx = (row >> 4) * 512 + ((row & 15) + 16 * ((k4 >> 1) & 3)) * 8 + (k4 & 1) * 4;
        *(short4*)&buf[idx] = o;
      };
      // hoist: issue ALL 28 chunk loads now (independent; compiler pipelines)
      StReg regs[28];
#pragma unroll
      for (int c = 0; c < 28; ++c) regs[c] = stage_load(c);
      __syncthreads();  // denl visible before stores that use it
#pragma unroll
      for (int c = 0; c < 4; ++c) stage_store(sm.g.stage[c], c, regs[c]);
      LBAR();
      {
        const int msl = wv >> 1, nh = wv & 1;
        const int rr = nh * 16 + s;
        const int gg = rr >> 3, jj = rr & 7;
        const size_t wrow = (size_t)(gg * 512 + j0 + jj) * 896;
        f4 acc = {0.f, 0.f, 0.f, 0.f};
#pragma unroll
        for (int c = 0; c < 28; ++c) {
          bf8 a = *(const bf8*)&sm.g.stage[c & 3][msl * 512 + lane * 8];
          bf8 bb = *(const bf8*)&Wc[wrow + c * 32 + q * 8];
          acc = __builtin_amdgcn_mfma_f32_16x16x32_bf16(a, bb, acc, 0, 0, 0);
          LBAR();
          if (c + 4 < 28) stage_store(sm.g.stage[(c + 4) & 3], c + 4, regs[c + 4]);
        }
        LBAR();  // all MFMA reads done before gbuf aliases stage
        float* gbuf = (float*)sm.g.stage;
#pragma unroll
        for (int reg = 0; reg < 4; ++reg) {
          int bat = msl * 16 + q * 4 + reg;
          gbuf[bat * 33 + rr] = acc[reg];
        }
      }
      LBAR();
      {
        const float* gbuf = (const float*)sm.g.stage;
        int b = tid >> 3, jj = tid & 7, j = j0 + jj;
        float gi = gbuf[b * 33 + jj] + bih[j] + bhh[j];
        float gf = gbuf[b * 33 + 8 + jj] + bih[512 + j] + bhh[512 + j];
        float gg2 = gbuf[b * 33 + 16 + jj] + bih[1024 + j] + bhh[1024 + j];
        float go = gbuf[b * 33 + 24 + jj] + bih[1536 + j] + bhh[1536 + j];
        float co = (t == 0) ? 0.f : cst[b * 512 + j];  // private cached
        float cn = sigf(gf) * co + sigf(gi) * tanhf(gg2);
        float hn = sigf(go) * tanhf(cn);
        cst[b * 512 + j] = cn;
        union { __hip_bfloat16 b16; unsigned short us; } hu;
        hu.b16 = __float2bfloat16(hn);
        st_coh2(hN + b * 512 + j, (unsigned)hu.us);
      }
    } else if (blockIdx.x < 128) {
      // ---- finalize step t-1: denoms -> sdW, usage update, argmin -> lu ----
      if (t > 0) {
        const int b = blockIdx.x - 64;
        f4 dp0, dp1, dp2, dp3, sm2;
        unsigned luv;
        asm volatile(
            "global_load_dwordx4 %0, %6, off sc0 sc1\n\t"
            "global_load_dwordx4 %1, %7, off sc0 sc1\n\t"
            "global_load_dwordx4 %2, %8, off sc0 sc1\n\t"
            "global_load_dwordx4 %3, %9, off sc0 sc1\n\t"
            "global_load_dwordx4 %4, %10, off sc0 sc1\n\t"
            "global_load_dword %5, %11, off sc0 sc1\n\t"
            "s_waitcnt vmcnt(0)"
            : "=&v"(dp0), "=&v"(dp1), "=&v"(dp2), "=&v"(dp3), "=&v"(sm2), "=&v"(luv)
            : "v"((const void*)(dp + (b * 4 + 0) * 4)),
              "v"((const void*)(dp + (b * 4 + 1) * 4)),
              "v"((const void*)(dp + (b * 4 + 2) * 4)),
              "v"((const void*)(dp + (b * 4 + 3) * 4)),
              "v"((const void*)(sdM2 + b * 4)), "v"((const void*)(lu + b))
            : "memory");
        float d0 = dp0.x + dp0.y + dp0.z + dp0.w;
        float d1 = dp1.x + dp1.y + dp1.z + dp1.w;
        float d2 = dp2.x + dp2.y + dp2.z + dp2.w;
        float d3 = dp3.x + dp3.y + dp3.z + dp3.w;
        if (tid == 0) { f4 dv = {d0, d1, d2, d3}; st_coh16(sdW + b * 4, dv); }
        float iC0 = 1.f / d0, iC1 = 1.f / d1, iC2 = 1.f / d2, iC3 = 1.f / d3;
        float iO0 = 0, iO1 = 0, iO2 = 0, iO3 = 0;
        if (t > 1) { iO0 = 1.f / sm2.x; iO1 = 1.f / sm2.y; iO2 = 1.f / sm2.z; iO3 = 1.f / sm2.w; }
        const float sa = sigf(alphap[0]);
        const float ga = gammap[0];
        const int luB = (int)luv;
        f4 ec[4], eo[4];
        {
          const void* pc[4]; const void* po[4];
#pragma unroll
          for (int i = 0; i < 4; ++i) {
            int n = i * 512 + tid;
            pc[i] = (const void*)(rwM1 + ((size_t)b * 2048 + n) * 4);
            po[i] = (const void*)(rwM2 + ((size_t)b * 2048 + n) * 4);
          }
          LD8X4(ec[0], ec[1], ec[2], ec[3], eo[0], eo[1], eo[2], eo[3],
                pc[0], pc[1], pc[2], pc[3], po[0], po[1], po[2], po[3]);
        }
        float vm = INFINITY;
        int im = 0x7fffffff;
#pragma unroll
        for (int i = 0; i < 4; ++i) {
          int n = i * 512 + tid;
          float wps = (t > 1) ? (eo[i].x * iO0 + eo[i].y * iO1 + eo[i].z * iO2 + eo[i].w * iO3)
                              : 0.f;
          float ww = sa * wps + (1.f - sa) * ((n == luB) ? 1.f : 0.f);
          float sn = ec[i].x * iC0 + ec[i].y * iC1 + ec[i].z * iC2 + ec[i].w * iC3;
          float uo = (t == 1) ? 0.f : usage[b * 2048 + n];  // private cached
          float u = ga * uo + sn + ww;
          usage[b * 2048 + n] = u;
          if (u < vm) { vm = u; im = n; }  // n strictly increasing per thread
        }
        sm.m.sv[tid] = vm; sm.m.si[tid] = im;
        LBAR();
        for (int off = 256; off > 0; off >>= 1) {
          if (tid < off) {
            float v2 = sm.m.sv[tid + off]; int j2 = sm.m.si[tid + off];
            if (v2 < sm.m.sv[tid] || (v2 == sm.m.sv[tid] && j2 < sm.m.si[tid])) {
              sm.m.sv[tid] = v2; sm.m.si[tid] = j2;
            }
          }
          LBAR();
        }
        if (tid == 0) st_coh4u(lu + b, (unsigned)sm.m.si[0]);
      }
    } else if (blockIdx.x < 192) {
      // ---- zero rvW for PA_t's atomics ----
      const int bz = blockIdx.x - 128;
      if (tid < 64) { f4 z = {0, 0, 0, 0}; st_coh16(rvW + bz * 256 + tid * 4, z); }
    }
    gsync(bar, ++rnd);

    // ========== PA phase: keys/out + fused M-pass (M in LDS) ==========
    {
      const int b = blockIdx.x >> 2, ch = blockIdx.x & 3;
      if (tid < 128) {
        union { ull u; uint2 v; } hv;
        hv.u = ald8(hN + b * 512 + tid * 4);
        *(uint2*)&sm.a.hs[tid * 4] = hv.v;
      }
      if (tid < 256) sm.a.rvacc[tid] = 0.f;
      unsigned luv = 0;
      if (t > 0) {
        luv = ald4(lu + b);
        // precompute w_prev sums: wps[nl] = sum_r exp_{t-1}[r]/denom_{t-1}[r]
        union { ull u; float2 f; } s0, s1, e0, e1;
        s0.u = ald8(sdW + b * 4); s1.u = ald8(sdW + b * 4 + 2);
        const size_t eb = ((size_t)b * 2048 + ch * 512 + tid) * 4;
        e0.u = ald8(rwM1 + eb); e1.u = ald8(rwM1 + eb + 2);
        sm.a.wps[tid] = e0.f.x / s0.f.x + e0.f.y / s0.f.y +
                        e1.f.x / s1.f.x + e1.f.y / s1.f.y;
      } else {
        sm.a.wps[tid] = 0.f;
      }
      __syncthreads();
      // keys (redundant per block) + out slice: 352 rows = 11 passes x 32
      for (int pp = 0; pp < 11; ++pp) {
        int idx = pp * 32 + wv * 4 + q;
        int wr; float bias;
        if (idx < 320) { wr = 128 + idx; bias = bkeyp[idx]; }
        else { wr = ch * 32 + (idx - 320); bias = boutp[wr]; }
        float acc = 0.f;
#pragma unroll
        for (int i = 0; i < 4; ++i) {
          bf8 w8 = *(const bf8*)&Wkb[(size_t)wr * 512 + i * 128 + s * 8];
          bf8 h8 = *(const bf8*)&sm.a.hs[i * 128 + s * 8];
#pragma unroll
          for (int j = 0; j < 8; ++j) acc += (float)w8[j] * (float)h8[j];
        }
        acc = red16(acc) + bias;
        if (s == 0) {
          if (idx < 256) sm.a.kbuf[idx] = acc;
          else if (idx < 320) sm.a.wkbuf[idx - 256] = acc;
          else out[((size_t)t * 64 + b) * 128 + wr] = acc;  // normal store
        }
      }
      LBAR();
      float4 kn[4];
#pragma unroll
      for (int r = 0; r < 4; ++r) {
        float4 k4 = *(float4*)&sm.a.kbuf[r * 64 + s * 4];
        float ss = k4.x * k4.x + k4.y * k4.y + k4.z * k4.z + k4.w * k4.w;
        ss = red16(ss);
        float iv = 1.f / (sqrtf(ss) + EPSF);
        kn[r].x = k4.x * iv; kn[r].y = k4.y * iv;
        kn[r].z = k4.z * iv; kn[r].w = k4.w * iv;
      }
      const float4 wk = *(float4*)&sm.a.wkbuf[s * 4];
      const float sa = sigf(alphap[0]);
      const int luB = (int)luv;
      float4 rva0 = {0,0,0,0}, rva1 = {0,0,0,0}, rva2 = {0,0,0,0}, rva3 = {0,0,0,0};
      float es0 = 0.f, es1 = 0.f, es2 = 0.f, es3 = 0.f;
      for (int i = 0; i < 16; ++i) {
        const int nl = wv * 64 + i * 4 + q;
        const int n = ch * 512 + nl;
        float4 m4;
        if (t > 0) m4 = *(float4*)&Mlds[nl * 64 + s * 4];
        else { m4.x = 1e-6f; m4.y = 1e-6f; m4.z = 1e-6f; m4.w = 1e-6f; }
        float ssm = m4.x * m4.x + m4.y * m4.y + m4.z * m4.z + m4.w * m4.w;
        float d0 = m4.x * kn[0].x + m4.y * kn[0].y + m4.z * kn[0].z + m4.w * kn[0].w;
        float d1 = m4.x * kn[1].x + m4.y * kn[1].y + m4.z * kn[1].z + m4.w * kn[1].w;
        float d2 = m4.x * kn[2].x + m4.y * kn[2].y + m4.z * kn[2].z + m4.w * kn[2].w;
        float d3 = m4.x * kn[3].x + m4.y * kn[3].y + m4.z * kn[3].z + m4.w * kn[3].w;
        ssm = red16(ssm);
        d0 = red16(d0); d1 = red16(d1); d2 = red16(d2); d3 = red16(d3);
        float iv = 1.f / (sqrtf(ssm) + EPSF);
        float e0 = __expf(d0 * iv), e1 = __expf(d1 * iv);
        float e2 = __expf(d2 * iv), e3 = __expf(d3 * iv);
        rva0.x += e0 * m4.x; rva0.y += e0 * m4.y; rva0.z += e0 * m4.z; rva0.w += e0 * m4.w;
        rva1.x += e1 * m4.x; rva1.y += e1 * m4.y; rva1.z += e1 * m4.z; rva1.w += e1 * m4.w;
        rva2.x += e2 * m4.x; rva2.y += e2 * m4.y; rva2.z += e2 * m4.z; rva2.w += e2 * m4.w;
        rva3.x += e3 * m4.x; rva3.y += e3 * m4.y; rva3.z += e3 * m4.z; rva3.w += e3 * m4.w;
        if (s == 0) {
          f4 ev = {e0, e1, e2, e3};
          st_coh16(rwCur + ((size_t)b * 2048 + n) * 4, ev);  // for finalize/wps
          es0 += e0; es1 += e1; es2 += e2; es3 += e3;
        }
        float wps = sm.a.wps[nl];
        float onehot = (n == luB) ? 1.f : 0.f;
        float ww = sa * wps + (1.f - sa) * onehot;
        float keep = 1.f - onehot;
        float4 mn;
        mn.x = m4.x * keep + ww * wk.x;
        mn.y = m4.y * keep + ww * wk.y;
        mn.z = m4.z * keep + ww * wk.z;
        mn.w = m4.w * keep + ww * wk.w;
        *(float4*)&Mlds[nl * 64 + s * 4] = mn;  // LDS-resident M
      }
      es0 += __shfl_xor(es0, 16); es0 += __shfl_xor(es0, 32);
      es1 += __shfl_xor(es1, 16); es1 += __shfl_xor(es1, 32);
      es2 += __shfl_xor(es2, 16); es2 += __shfl_xor(es2, 32);
      es3 += __shfl_xor(es3, 16); es3 += __shfl_xor(es3, 32);
      if (lane == 0) {
        sm.a.wsum[wv * 4 + 0] = es0; sm.a.wsum[wv * 4 + 1] = es1;
        sm.a.wsum[wv * 4 + 2] = es2; sm.a.wsum[wv * 4 + 3] = es3;
      }
#define REDQ(v) { v += __shfl_xor(v, 16); v += __shfl_xor(v, 32); }
      REDQ(rva0.x) REDQ(rva0.y) REDQ(rva0.z) REDQ(rva0.w)
      REDQ(rva1.x) REDQ(rva1.y) REDQ(rva1.z) REDQ(rva1.w)
      REDQ(rva2.x) REDQ(rva2.y) REDQ(rva2.z) REDQ(rva2.w)
      REDQ(rva3.x) REDQ(rva3.y) REDQ(rva3.z) REDQ(rva3.w)
#undef REDQ
      if (q == 0) {
        atomicAdd(&sm.a.rvacc[0 * 64 + s * 4 + 0], rva0.x);
        atomicAdd(&sm.a.rvacc[0 * 64 + s * 4 + 1], rva0.y);
        atomicAdd(&sm.a.rvacc[0 * 64 + s * 4 + 2], rva0.z);
        atomicAdd(&sm.a.rvacc[0 * 64 + s * 4 + 3], rva0.w);
        atomicAdd(&sm.a.rvacc[1 * 64 + s * 4 + 0], rva1.x);
        atomicAdd(&sm.a.rvacc[1 * 64 + s * 4 + 1], rva1.y);
        atomicAdd(&sm.a.rvacc[1 * 64 + s * 4 + 2], rva1.z);
        atomicAdd(&sm.a.rvacc[1 * 64 + s * 4 + 3], rva1.w);
        atomicAdd(&sm.a.rvacc[2 * 64 + s * 4 + 0], rva2.x);
        atomicAdd(&sm.a.rvacc[2 * 64 + s * 4 + 1], rva2.y);
        atomicAdd(&sm.a.rvacc[2 * 64 + s * 4 + 2], rva2.z);
        atomicAdd(&sm.a.rvacc[2 * 64 + s * 4 + 3], rva2.w);
        atomicAdd(&sm.a.rvacc[3 * 64 + s * 4 + 0], rva3.x);
        atomicAdd(&sm.a.rvacc[3 * 64 + s * 4 + 1], rva3.y);
        atomicAdd(&sm.a.rvacc[3 * 64 + s * 4 + 2], rva3.z);
        atomicAdd(&sm.a.rvacc[3 * 64 + s * 4 + 3], rva3.w);
      }
      LBAR();
      if (tid < 4) {
        float ssum = 0.f;
        for (int w8 = 0; w8 < 8; ++w8) ssum += sm.a.wsum[w8 * 4 + tid];
        st_coh4(dp + (b * 4 + tid) * 4 + ch, ssum);  // denom partial
      }
      if (tid < 256) {
        float v = sm.a.rvacc[tid];
        atomicAdd(rvW + b * 256 + tid, v);  // device-scope, at MALL
      }
    }
    gsync(bar, ++rnd);
  }
}

extern "C" void kernel_launch(void* const* d_in, const int* in_sizes, int n_in,
                              void* d_out, int out_size, void* d_ws, size_t ws_size,
                              hipStream_t stream) {
  const float* x_seq = (const float*)d_in[0];
  const float* Wih = (const float*)d_in[1];
  const float* Whh = (const float*)d_in[2];
  const float* bih = (const float*)d_in[3];
  const float* bhh = (const float*)d_in[4];
  const float* Wout = (const float*)d_in[5];
  const float* bout = (const float*)d_in[6];
  const float* Wkey = (const float*)d_in[7];
  const float* bkey = (const float*)d_in[8];
  const float* alpha = (const float*)d_in[9];
  const float* gamma = (const float*)d_in[10];
  float* out = (float*)d_out;
  char* ws = (char*)d_ws;

  // zero the barrier flag region (ws is re-poisoned before every call)
  hipMemsetAsync(ws + 38673408, 0, 20480, stream);
  mann_mega<<<256, 512, 0, stream>>>(x_seq, Wih, Whh, bih, bhh, Wout, bout,
                                     Wkey, bkey, alpha, gamma, out, ws);
}